// Round 9
// baseline (153.456 us; speedup 1.0000x reference)
//
#include <hip/hip_runtime.h>
#include <math.h>

#define NB 1024
#define NC 63
#define NF 250
#define NH 4
#define ND 250
#define NHD 1000

typedef __bf16 bf16x8 __attribute__((ext_vector_type(8)));
typedef float f32x4 __attribute__((ext_vector_type(4)));

// ============================================================================
// k_adj_mfma: per-batch 64x64 gram via bf16 MFMA with hi/lo split (unchanged).
// ============================================================================
__global__ __launch_bounds__(256) void k_adj_mfma(const float* __restrict__ x,
                                                  float* __restrict__ partial) {
    __shared__ __align__(16) __bf16 Xh[64 * 256];   // 32 KB
    __shared__ __align__(16) __bf16 Xl[64 * 256];   // 32 KB
    __shared__ float sS[64], ssS[64], meanv[64], sclv[64];
    const int t = threadIdx.x;
    const int w = t >> 6, l = t & 63;
    const int l16 = l & 15, lq = l >> 4;
    const int swz = (l16 & 7) << 3;

    {
        const int kz = t ^ ((63 & 7) << 3);
        Xh[63 * 256 + kz] = (__bf16)1.0f;
        Xl[63 * 256 + kz] = (__bf16)0.0f;
    }

    float adjacc[4][4];
#pragma unroll
    for (int ni = 0; ni < 4; ++ni)
#pragma unroll
        for (int r = 0; r < 4; ++r) adjacc[ni][r] = 0.f;

    for (int bb = 0; bb < 4; ++bb) {
        const float* xb = x + (size_t)(blockIdx.x * 4 + bb) * (NC * NF);
#pragma unroll
        for (int it = 0; it < 8; ++it) {
            const int u = it * 256 + t;
            if (u < 2016) {
                const int row = u >> 5;
                const int ko = (u & 31) << 3;
                const float* src = xb + row * NF + ko;
                float v[8];
#pragma unroll
                for (int q = 0; q < 4; ++q) {
                    if (ko + q * 2 < NF) {
                        const float2 p = *(const float2*)(src + q * 2);
                        v[2 * q] = p.x; v[2 * q + 1] = p.y;
                    } else { v[2 * q] = 0.f; v[2 * q + 1] = 0.f; }
                }
                bf16x8 h, lo_;
#pragma unroll
                for (int j = 0; j < 8; ++j) {
                    h[j] = (__bf16)v[j];
                    lo_[j] = (__bf16)(v[j] - (float)h[j]);
                }
                const int kS = ko ^ ((row & 7) << 3);
                *(bf16x8*)&Xh[row * 256 + kS] = h;
                *(bf16x8*)&Xl[row * 256 + kS] = lo_;
            }
        }
        __syncthreads();

        f32x4 acc[4];
        const f32x4 z4 = {0.f, 0.f, 0.f, 0.f};
#pragma unroll
        for (int ni = 0; ni < 4; ++ni) acc[ni] = z4;
        const int arow = 16 * w + l16;
#pragma unroll
        for (int kc = 0; kc < 8; ++kc) {
            const int kb = (kc * 32 + lq * 8) ^ swz;
            const bf16x8 ah = *(const bf16x8*)&Xh[arow * 256 + kb];
            const bf16x8 al = *(const bf16x8*)&Xl[arow * 256 + kb];
#pragma unroll
            for (int ni = 0; ni < 4; ++ni) {
                const int brow = 16 * ni + l16;
                const bf16x8 bh = *(const bf16x8*)&Xh[brow * 256 + kb];
                const bf16x8 bl = *(const bf16x8*)&Xl[brow * 256 + kb];
                acc[ni] = __builtin_amdgcn_mfma_f32_16x16x32_bf16(ah, bh, acc[ni], 0, 0, 0);
                acc[ni] = __builtin_amdgcn_mfma_f32_16x16x32_bf16(ah, bl, acc[ni], 0, 0, 0);
                acc[ni] = __builtin_amdgcn_mfma_f32_16x16x32_bf16(al, bh, acc[ni], 0, 0, 0);
            }
        }

        if (l16 == 15) {
#pragma unroll
            for (int r = 0; r < 4; ++r) sS[16 * w + lq * 4 + r] = acc[3][r];
        }
        if ((l16 >> 2) == lq) ssS[16 * w + l16] = acc[w][l16 & 3];
        __syncthreads();
        if (t < 64) {
            const float S = sS[t], SSv = ssS[t];
            float m = S * (1.f / (float)NF);
            const float var = (SSv - S * S * (1.f / (float)NF)) * (1.f / (float)(NF - 1));
            float sc = 1.f / (sqrtf(var) + 1e-8f);
            if (t >= NC) { m = 0.f; sc = 0.f; }
            meanv[t] = m; sclv[t] = sc;
        }
        __syncthreads();

        float mr[4], sr[4];
#pragma unroll
        for (int r = 0; r < 4; ++r) {
            const int row = 16 * w + lq * 4 + r;
            mr[r] = meanv[row]; sr[r] = sclv[row];
        }
#pragma unroll
        for (int ni = 0; ni < 4; ++ni) {
            const float mc = meanv[16 * ni + l16];
            const float sc = sclv[16 * ni + l16];
#pragma unroll
            for (int r = 0; r < 4; ++r)
                adjacc[ni][r] += (acc[ni][r] - (float)NF * mr[r] * mc) * sr[r] * sc;
        }
    }

#pragma unroll
    for (int ni = 0; ni < 4; ++ni)
#pragma unroll
        for (int r = 0; r < 4; ++r) {
            const int row = 16 * w + lq * 4 + r;
            const int col = 16 * ni + l16;
            partial[(size_t)blockIdx.x * 4096 + row * 64 + col] = adjacc[ni][r];
        }
}

// ============================================================================
// Reduce 256 partials -> adj (63x63). grid 63 rows x 512 thr. (unchanged)
// ============================================================================
__global__ __launch_bounds__(512) void k_adj_reduce(const float* __restrict__ partial,
                                                    float* __restrict__ adj) {
    __shared__ float red[8][64];
    const int row = blockIdx.x, t = threadIdx.x;
    const int c = t & 63, g = t >> 6;
    float s = 0.f;
    const float* p = partial + (size_t)(g * 32) * 4096 + row * 64 + c;
#pragma unroll 8
    for (int i = 0; i < 32; ++i) s += p[(size_t)i * 4096];
    red[g][c] = s;
    __syncthreads();
    if (t < NC) {
        float tot = 0.f;
#pragma unroll
        for (int gg = 0; gg < 8; ++gg) tot += red[gg][t];
        adj[row * NC + t] = tot * (1.f / ((float)NF * (float)NB));
    }
}

// ============================================================================
// k_gs: gs[f][h] = Wg[f, h-slice] . att_src[h],  gd likewise. (unchanged)
// ============================================================================
__global__ __launch_bounds__(256) void k_gs(const float* __restrict__ Wg,
                                            const float* __restrict__ att_src,
                                            const float* __restrict__ att_dst,
                                            float* __restrict__ gs,
                                            float* __restrict__ gd) {
    const int f = blockIdx.x;
    const int h = threadIdx.x >> 6, l = threadIdx.x & 63;
    const float* wr = Wg + (size_t)f * NHD + h * ND;
    const float* sp = att_src + h * ND;
    const float* dp = att_dst + h * ND;
    float s = 0.f, d = 0.f;
#pragma unroll
    for (int q = 0; q < 4; ++q) {
        const int dd = l + q * 64;
        if (dd < ND) {
            const float wv = wr[dd];
            s += wv * sp[dd];
            d += wv * dp[dd];
        }
    }
#pragma unroll
    for (int off = 32; off >= 1; off >>= 1) {
        s += __shfl_down(s, off);
        d += __shfl_down(d, off);
    }
    if (l == 0) { gs[f * NH + h] = s; gd[f * NH + h] = d; }
}

// ============================================================================
// k_asad: as[c,h] = x0[c] . gs[:,h]. One block. (unchanged)
// ============================================================================
__global__ __launch_bounds__(512) void k_asad(const float* __restrict__ x,
                                              const float* __restrict__ gs,
                                              const float* __restrict__ gd,
                                              float* __restrict__ as_,
                                              float* __restrict__ ad_) {
    __shared__ float x0S[NC * NF];       // 61.5 KB
    __shared__ float gsS[NF * NH], gdS[NF * NH];
    const int t = threadIdx.x;
    for (int e = t; e < NC * NF; e += 512) x0S[e] = x[e];
    for (int e = t; e < NF * NH; e += 512) { gsS[e] = gs[e]; gdS[e] = gd[e]; }
    __syncthreads();
    if (t < NC * NH) {
        const int c = t >> 2, h = t & 3;
        float s = 0.f, d = 0.f;
#pragma unroll 5
        for (int f = 0; f < NF; ++f) {
            const float xv = x0S[c * NF + f];
            s += xv * gsS[f * NH + h];
            d += xv * gdS[f * NH + h];
        }
        as_[t] = s; ad_[t] = d;
    }
}

// ============================================================================
// k_out0 v4: register softmax + projection over hp (K=256). (unchanged)
// ============================================================================
__global__ __launch_bounds__(512) void k_out0(const float* __restrict__ adj,
                                              const float* __restrict__ as_,
                                              const float* __restrict__ ad_,
                                              const float* __restrict__ hp,
                                              const float* __restrict__ biasc,
                                              float* __restrict__ out) {
    __shared__ float adjS[NC * NC];
    __shared__ float thS[NC];
    __shared__ float asS[NC * 5];        // stride-5 pad
    __shared__ float adS[NC * NH];
    __shared__ float wS[256];            // w[h*64+i], zeros at i=63
    __shared__ float psum[2][256];
    const int j = blockIdx.x, t = threadIdx.x;
    const int w = t >> 6, l = t & 63;

    for (int e = t; e < NC * NC; e += 512) adjS[e] = adj[e];
    if (t < NC * NH) { asS[(t >> 2) * 5 + (t & 3)] = as_[t]; adS[t] = ad_[t]; }
    __syncthreads();

    for (int r = w; r < NC; r += 8) {
        const float v = (l < NC) ? adjS[r * NC + l] : -INFINITY;
        float prev = INFINITY;
        int krem = 8;                     // TOP_K
        float th = -INFINITY;
#pragma unroll
        for (int iter = 0; iter < 8; ++iter) {
            const float vm = (v < prev) ? v : -INFINITY;
            float m = vm;
#pragma unroll
            for (int off = 32; off >= 1; off >>= 1) m = fmaxf(m, __shfl_xor(m, off));
            const unsigned long long b = __ballot(vm == m);
            const int cnt = __popcll(b);
            if (cnt >= krem) { th = m; break; }
            krem -= cnt; prev = m;
        }
        if (l == 0) thS[r] = th;
    }
    __syncthreads();

    if (w < NH) {
        const int h = w, i = l;
        const float adv = adS[j * NH + h];
        const float a = (i < NC) ? adjS[i * NC + j] : 0.f;
        const bool msk = (i < NC) && ((i == j) || ((a >= thS[i]) && (a != 0.f)));
        float e = 0.f;
        if (msk) { e = asS[i * 5 + h] + adv; e = e > 0.f ? e : 0.2f * e; }
        float m = msk ? e : -INFINITY;
#pragma unroll
        for (int off = 32; off >= 1; off >>= 1) m = fmaxf(m, __shfl_xor(m, off));
        const float p = msk ? __expf(e - m) : 0.f;
        float s = p;
#pragma unroll
        for (int off = 32; off >= 1; off >>= 1) s += __shfl_xor(s, off);
        wS[(h << 6) + l] = p / s;        // 0 for i=63 / unmasked
    }
    __syncthreads();

    const int q = t >> 8, col = t & 255;
    float acc = 0.f;
    const float* hpc = hp + col;
#pragma unroll 8
    for (int e = q * 128; e < q * 128 + 128; ++e)
        acc += wS[e] * hpc[(size_t)e * 256];
    psum[q][col] = acc;
    __syncthreads();
    if (t < ND) out[(size_t)j * ND + t] = psum[0][t] + psum[1][t] + biasc[t];
}

// ============================================================================
// Wc split-K x8 partials, stored TRANSPOSED pWcT[kq][n][256f]. (unchanged)
// ============================================================================
__global__ __launch_bounds__(256) void k_wc_part(const float* __restrict__ Wg,
                                                 const float* __restrict__ bias_gat,
                                                 const float* __restrict__ Wp,
                                                 float* __restrict__ pWcT,
                                                 float* __restrict__ pbias) {
    __shared__ float rows[250];
    const int b = blockIdx.x, t = threadIdx.x;
    if (b < 1000) {
        const int fb = (b >> 3) * 2, kq = b & 7;
        if (t < 250)
            rows[t] = Wg[(size_t)(fb + t / 125) * NHD + kq * 125 + (t % 125)];
        __syncthreads();
        if (t < ND) {
            float a0 = 0.f, a1 = 0.f;
            const float* wp = Wp + (size_t)(kq * 125) * ND + t;
            for (int k = 0; k < 125; ++k) {
                float wv = wp[(size_t)k * ND];
                a0 += rows[k] * wv;
                a1 += rows[125 + k] * wv;
            }
            pWcT[(size_t)kq * 65536 + (size_t)t * 256 + fb] = a0;
            pWcT[(size_t)kq * 65536 + (size_t)t * 256 + fb + 1] = a1;
        }
    } else {
        const int kq = b - 1000;
        if (t < ND) {
            float acc = 0.f;
            for (int k = kq * 125; k < kq * 125 + 125; ++k)
                acc += bias_gat[k] * Wp[(size_t)k * ND + t];
            pbias[kq * 256 + t] = acc;
        }
    }
}

// ============================================================================
// Combine: WcT + per-head WchT bf16; block 256 does biasc. (unchanged)
// ============================================================================
__global__ __launch_bounds__(256) void k_wct(const float* __restrict__ pWcT,
                                             const float* __restrict__ pbias,
                                             const float* __restrict__ b_proj,
                                             __bf16* __restrict__ WcT,
                                             __bf16* __restrict__ WchT,
                                             float* __restrict__ biasc) {
    const int n = blockIdx.x, t = threadIdx.x;
    if (n < 256) {
        float v[8];
        float tot = 0.f;
#pragma unroll
        for (int kq = 0; kq < 8; ++kq) {
            float xv = 0.f;
            if (n < ND && t < NF) xv = pWcT[(size_t)kq * 65536 + (size_t)n * 256 + t];
            v[kq] = xv; tot += xv;
        }
        WcT[n * 256 + t] = (__bf16)tot;
#pragma unroll
        for (int h = 0; h < NH; ++h)
            WchT[h * 65536 + n * 256 + t] = (__bf16)(v[2 * h] + v[2 * h + 1]);
    } else {
        if (t < ND) {
            float v = 0.f;
#pragma unroll
            for (int kq = 0; kq < 8; ++kq) v += pbias[kq * 256 + t];
            biasc[t] = v + b_proj[t];
        }
    }
}

// ============================================================================
// k_hp: hp[h*64+i][col] = x0[i] @ Wch[h] via MFMA (grid 4 = h). (unchanged)
// ============================================================================
__global__ __launch_bounds__(256) void k_hp(const float* __restrict__ x,
                                            const __bf16* __restrict__ WchT,
                                            float* __restrict__ hp) {
    __shared__ __align__(16) __bf16 Xs[64 * 256];
    const int h = blockIdx.x;
    const int t = threadIdx.x;
    const int w = t >> 6, l = t & 63;
    const int l16 = l & 15, lq = l >> 4;
    const int nb = w * 64;
    const int swz = (l16 & 7) << 3;

    bf16x8 bfr[4][8];
    const __bf16* Wh = WchT + h * 65536;
#pragma unroll
    for (int ni = 0; ni < 4; ++ni) {
        const int n = nb + ni * 16 + l16;
#pragma unroll
        for (int kc = 0; kc < 8; ++kc)
            bfr[ni][kc] = *(const bf16x8*)(Wh + (size_t)n * 256 + kc * 32 + lq * 8);
    }

#pragma unroll
    for (int it = 0; it < 8; ++it) {
        const int u = it * 256 + t;
        const int row = u >> 5;
        const int ko = (u & 31) << 3;
        float v[8];
#pragma unroll
        for (int q = 0; q < 4; ++q) { v[2 * q] = 0.f; v[2 * q + 1] = 0.f; }
        if (row < NC) {
            const float* src = x + row * NF + ko;
#pragma unroll
            for (int q = 0; q < 4; ++q) {
                if (ko + 2 * q + 1 < NF) {
                    const float2 p = *(const float2*)(src + 2 * q);
                    v[2 * q] = p.x; v[2 * q + 1] = p.y;
                }
            }
        }
        bf16x8 hv;
#pragma unroll
        for (int jj = 0; jj < 8; ++jj) hv[jj] = (__bf16)v[jj];
        *(bf16x8*)&Xs[row * 256 + (ko ^ ((row & 7) << 3))] = hv;
    }
    __syncthreads();

    f32x4 acc[4][4];
    const f32x4 z4 = {0.f, 0.f, 0.f, 0.f};
#pragma unroll
    for (int mi = 0; mi < 4; ++mi)
#pragma unroll
        for (int ni = 0; ni < 4; ++ni) acc[mi][ni] = z4;

#pragma unroll
    for (int kc = 0; kc < 8; ++kc) {
        const int kb = (kc * 32 + lq * 8) ^ swz;
        bf16x8 afr[4];
#pragma unroll
        for (int mi = 0; mi < 4; ++mi)
            afr[mi] = *(const bf16x8*)&Xs[(mi * 16 + l16) * 256 + kb];
#pragma unroll
        for (int mi = 0; mi < 4; ++mi)
#pragma unroll
            for (int ni = 0; ni < 4; ++ni)
                acc[mi][ni] = __builtin_amdgcn_mfma_f32_16x16x32_bf16(
                    afr[mi], bfr[ni][kc], acc[mi][ni], 0, 0, 0);
    }

#pragma unroll
    for (int mi = 0; mi < 4; ++mi)
#pragma unroll
        for (int r = 0; r < 4; ++r) {
            const int row = mi * 16 + lq * 4 + r;
#pragma unroll
            for (int ni = 0; ni < 4; ++ni) {
                const int col = nb + ni * 16 + l16;
                hp[(size_t)(h * 64 + row) * 256 + col] = acc[mi][ni][r];
            }
        }
}

// ============================================================================
// MAIN v4: out = x @ Wc + biasc via bf16 MFMA, pipelined staging.
// Fixes R8's stage-latency serialization (51us @ 2.1TB/s despite 20.5us
// memory floor):
//  - issue/convert SPLIT: all 32 A-loads (pv[8][4], 64 VGPR) issue with no
//    interleaved converts -> 1 HBM latency per tile instead of 8.
//    (ko=(t&31)*8 is it-independent -> guards are per-thread constants.)
//  - cross-tile prefetch (T14): tile1's A-loads issue right after tile0's
//    barrier, flying during tile0's MFMA+stores.
//  - B in half-K chunks bfr[4][4] (64 VGPR, reloaded from L2) to stay
//    <=256 unified regs -> 2 blocks/CU.
//  - double-buffered Xs (64KB) -> 1 barrier per tile.
// ============================================================================
__global__ __launch_bounds__(256, 2) void k_main_mfma(const float* __restrict__ x,
                                                      const __bf16* __restrict__ WcT,
                                                      const float* __restrict__ biasc,
                                                      float* __restrict__ out) {
    __shared__ __align__(16) __bf16 Xs[2][64 * 256];   // 64 KB
    const int t = threadIdx.x;
    const int w = t >> 6;
    const int l = t & 63;
    const int l16 = l & 15, lq = l >> 4;
    const int nb = w * 64;
    const int swz = (l16 & 7) << 3;
    const int ko = (t & 31) << 3;        // it-independent octet base
    const int r0 = t >> 5;               // row sub-base 0..7
    const float2 z2 = make_float2(0.f, 0.f);

    float bc[4];
#pragma unroll
    for (int ni = 0; ni < 4; ++ni) {
        const int col = nb + ni * 16 + l16;
        bc[ni] = (col < ND) ? biasc[col] : 0.f;
    }

    float2 pv[8][4];
    bf16x8 bfr[4][4];
    f32x4 acc[4][4];
    const f32x4 z4 = {0.f, 0.f, 0.f, 0.f};

    const size_t m0 = (size_t)blockIdx.x * 64;
    const size_t m1 = (size_t)(blockIdx.x + 504) * 64;

#define A_ISSUE(MB)                                                          \
    {                                                                        \
        _Pragma("unroll")                                                    \
        for (int it = 0; it < 8; ++it) {                                     \
            const float* src = x + ((MB) + it * 8 + r0) * NF + ko;           \
            pv[it][0] = *(const float2*)src;                                 \
            pv[it][1] = (ko + 3 < NF) ? *(const float2*)(src + 2) : z2;      \
            pv[it][2] = (ko + 5 < NF) ? *(const float2*)(src + 4) : z2;      \
            pv[it][3] = (ko + 7 < NF) ? *(const float2*)(src + 6) : z2;      \
        }                                                                    \
    }

#define B_ISSUE(HALF)                                                        \
    {                                                                        \
        _Pragma("unroll")                                                    \
        for (int ni = 0; ni < 4; ++ni) {                                     \
            const int n = nb + ni * 16 + l16;                                \
            _Pragma("unroll")                                                \
            for (int kk = 0; kk < 4; ++kk)                                   \
                bfr[ni][kk] = *(const bf16x8*)(WcT + (size_t)n * 256 +       \
                                               ((HALF) * 4 + kk) * 32 + lq * 8); \
        }                                                                    \
    }

#define CONVERT_WRITE(BUF)                                                   \
    {                                                                        \
        _Pragma("unroll")                                                    \
        for (int it = 0; it < 8; ++it) {                                     \
            const int row = it * 8 + r0;                                     \
            bf16x8 hv;                                                       \
            hv[0] = (__bf16)pv[it][0].x; hv[1] = (__bf16)pv[it][0].y;        \
            hv[2] = (__bf16)pv[it][1].x; hv[3] = (__bf16)pv[it][1].y;        \
            hv[4] = (__bf16)pv[it][2].x; hv[5] = (__bf16)pv[it][2].y;        \
            hv[6] = (__bf16)pv[it][3].x; hv[7] = (__bf16)pv[it][3].y;        \
            *(bf16x8*)&Xs[BUF][row * 256 + (ko ^ ((row & 7) << 3))] = hv;    \
        }                                                                    \
    }

#define MFMA_HALF(BUF, HALF)                                                 \
    {                                                                        \
        _Pragma("unroll")                                                    \
        for (int kk = 0; kk < 4; ++kk) {                                     \
            const int kb = (((HALF) * 4 + kk) * 32 + lq * 8) ^ swz;          \
            bf16x8 afr[4];                                                   \
            _Pragma("unroll")                                                \
            for (int mi = 0; mi < 4; ++mi)                                   \
                afr[mi] = *(const bf16x8*)&Xs[BUF][(mi * 16 + l16) * 256 + kb]; \
            _Pragma("unroll")                                                \
            for (int mi = 0; mi < 4; ++mi)                                   \
                _Pragma("unroll")                                            \
                for (int ni = 0; ni < 4; ++ni)                               \
                    acc[mi][ni] = __builtin_amdgcn_mfma_f32_16x16x32_bf16(   \
                        afr[mi], bfr[ni][kk], acc[mi][ni], 0, 0, 0);         \
        }                                                                    \
    }

#define STORES(MB)                                                           \
    {                                                                        \
        _Pragma("unroll")                                                    \
        for (int mi = 0; mi < 4; ++mi) {                                     \
            _Pragma("unroll")                                                \
            for (int r = 0; r < 4; ++r) {                                    \
                const size_t row = (MB) + mi * 16 + lq * 4 + r;              \
                _Pragma("unroll")                                            \
                for (int ni = 0; ni < 4; ++ni) {                             \
                    const int col = nb + ni * 16 + l16;                      \
                    if (col < ND)                                            \
                        out[row * ND + col] = acc[mi][ni][r] + bc[ni];       \
                }                                                            \
            }                                                                \
        }                                                                    \
    }

    // ================= tile 0 =================
    A_ISSUE(m0);
    B_ISSUE(0);
    CONVERT_WRITE(0);
    __syncthreads();
    A_ISSUE(m1);                         // prefetch tile 1 (flies during MFMA)
#pragma unroll
    for (int mi = 0; mi < 4; ++mi)
#pragma unroll
        for (int ni = 0; ni < 4; ++ni) acc[mi][ni] = z4;
    MFMA_HALF(0, 0);
    B_ISSUE(1);
    MFMA_HALF(0, 1);
    STORES(m0);

    // ================= tile 1 =================
    B_ISSUE(0);
    CONVERT_WRITE(1);                    // pv loads long since arrived
    __syncthreads();
#pragma unroll
    for (int mi = 0; mi < 4; ++mi)
#pragma unroll
        for (int ni = 0; ni < 4; ++ni) acc[mi][ni] = z4;
    MFMA_HALF(1, 0);
    B_ISSUE(1);
    MFMA_HALF(1, 1);
    STORES(m1);

#undef A_ISSUE
#undef B_ISSUE
#undef CONVERT_WRITE
#undef MFMA_HALF
#undef STORES
}

// ============================================================================
extern "C" void kernel_launch(void* const* d_in, const int* in_sizes, int n_in,
                              void* d_out, int out_size, void* d_ws, size_t ws_size,
                              hipStream_t stream) {
    const float* x       = (const float*)d_in[0];
    const float* Wg      = (const float*)d_in[1];
    const float* att_src = (const float*)d_in[2];
    const float* att_dst = (const float*)d_in[3];
    const float* bias_g  = (const float*)d_in[4];
    const float* Wp      = (const float*)d_in[5];
    const float* b_proj  = (const float*)d_in[6];
    float* out = (float*)d_out;
    float* ws  = (float*)d_ws;

    __bf16* WcT    = (__bf16*)ws;                 // 65536 bf16  = 32768 f
    __bf16* WchT   = (__bf16*)(ws + 32768);       // 4*65536 bf16 = 131072 f
    float* pWcT    = ws + 32768 + 131072;         // 8*65536 = 524288
    float* pbias   = pWcT + 8 * 65536;            // 2048
    float* biasc   = pbias + 2048;                // 256
    float* partial = biasc + 256;                 // 256*4096 = 1,048,576
    float* adj     = partial + 256 * 4096;        // 3969
    float* hp      = adj + NC * NC;               // 256*256 = 65536
    float* gs      = hp + 65536;                  // 1000
    float* gd      = gs + 1000;                   // 1000
    float* as_     = gd + 1000;                   // 252
    float* ad_     = as_ + 252;                   // 252  (total ~7.2 MB)

    k_wc_part<<<1008, 256, 0, stream>>>(Wg, bias_g, Wp, pWcT, pbias);
    k_wct<<<257, 256, 0, stream>>>(pWcT, pbias, b_proj, WcT, WchT, biasc);
    k_main_mfma<<<504, 256, 0, stream>>>(x, WcT, biasc, out);
    k_hp<<<4, 256, 0, stream>>>(x, WchT, hp);
    k_adj_mfma<<<256, 256, 0, stream>>>(x, partial);
    k_adj_reduce<<<63, 512, 0, stream>>>(partial, adj);
    k_gs<<<250, 256, 0, stream>>>(Wg, att_src, att_dst, gs, gd);
    k_asad<<<1, 512, 0, stream>>>(x, gs, gd, as_, ad_);
    k_out0<<<63, 512, 0, stream>>>(adj, as_, ad_, hp, biasc, out);
}

// Round 10
// 132.012 us; speedup vs baseline: 1.1624x; 1.1624x over previous
//
#include <hip/hip_runtime.h>
#include <math.h>

#define NB 1024
#define NC 63
#define NF 250
#define NH 4
#define ND 250
#define NHD 1000

typedef __bf16 bf16x8 __attribute__((ext_vector_type(8)));
typedef float f32x4 __attribute__((ext_vector_type(4)));

// ============================================================================
// k_fused: per-batch {main GEMM + gram} off ONE staged x-tile.
//   - x_b (63x250 fp32) staged once as Xh+Xl bf16 [64][256], XOR-swizzled
//     (adj_mfma's proven pattern); row 63 = ones (S via G[:,63], SS via diag).
//   - main: out[b*63+c] = x@Wc + biasc. A=Xh, B=WcT in regs (2 half-K chunks),
//     128 MFMA/wave. Identical numerics to R8 k_main (bf16 single).
//   - gram: G = Hh.Hh^T + Hh.Hl^T + Hl.Hh^T, 96 MFMA/wave; fixup
//     (G - F*m_i*m_j)*s_i*s_j accumulated over the block's 2 batches.
// grid 512 x 256 thr (4 waves); 2 batches/block serial; 3 barriers/batch;
// 64KB LDS -> 2 blocks/CU (stage of one overlaps MFMA of the other).
// Saves a full 64.5MB x re-read + a launch vs separate kernels.
// (R9 lesson: NO hand pipelining — compiler-scheduled staging was faster.)
// ============================================================================
__global__ __launch_bounds__(256) void k_fused(const float* __restrict__ x,
                                               const __bf16* __restrict__ WcT,
                                               const float* __restrict__ biasc,
                                               float* __restrict__ out,
                                               float* __restrict__ partial) {
    __shared__ __align__(16) __bf16 Xh[64 * 256];   // 32 KB
    __shared__ __align__(16) __bf16 Xl[64 * 256];   // 32 KB
    __shared__ float sS[64], ssS[64], meanv[64], sclv[64];
    const int t = threadIdx.x;
    const int w = t >> 6, l = t & 63;
    const int l16 = l & 15, lq = l >> 4;
    const int swz = (l16 & 7) << 3;
    const int nb = w * 64;

    // ones row (row 63) once: hi=1, lo=0 at swizzled positions
    {
        const int kz = t ^ ((63 & 7) << 3);
        Xh[63 * 256 + kz] = (__bf16)1.0f;
        Xl[63 * 256 + kz] = (__bf16)0.0f;
    }

    float bc[4];
#pragma unroll
    for (int ni = 0; ni < 4; ++ni) {
        const int col = nb + ni * 16 + l16;
        bc[ni] = (col < ND) ? biasc[col] : 0.f;
    }

    float adjacc[4][4];
#pragma unroll
    for (int ni = 0; ni < 4; ++ni)
#pragma unroll
        for (int r = 0; r < 4; ++r) adjacc[ni][r] = 0.f;

    const f32x4 z4 = {0.f, 0.f, 0.f, 0.f};

    for (int bb = 0; bb < 2; ++bb) {
        const int b = blockIdx.x * 2 + bb;
        const float* xb = x + (size_t)b * (NC * NF);

        // ---- stage: 63 rows x 32 octets, coalesced float2 -> hi/lo bf16
#pragma unroll
        for (int it = 0; it < 8; ++it) {
            const int u = it * 256 + t;
            if (u < 2016) {
                const int row = u >> 5;
                const int ko = (u & 31) << 3;
                const float* src = xb + row * NF + ko;
                float v[8];
#pragma unroll
                for (int q = 0; q < 4; ++q) {
                    if (ko + q * 2 < NF) {
                        const float2 p = *(const float2*)(src + q * 2);
                        v[2 * q] = p.x; v[2 * q + 1] = p.y;
                    } else { v[2 * q] = 0.f; v[2 * q + 1] = 0.f; }
                }
                bf16x8 h, lo_;
#pragma unroll
                for (int j = 0; j < 8; ++j) {
                    h[j] = (__bf16)v[j];
                    lo_[j] = (__bf16)(v[j] - (float)h[j]);
                }
                const int kS = ko ^ ((row & 7) << 3);
                *(bf16x8*)&Xh[row * 256 + kS] = h;
                *(bf16x8*)&Xl[row * 256 + kS] = lo_;
            }
        }
        __syncthreads();   // barrier 1: staging complete

        // ---- B half 0 preload (L2-resident WcT)
        bf16x8 bfr[4][4];
#pragma unroll
        for (int ni = 0; ni < 4; ++ni) {
            const int n = nb + ni * 16 + l16;
#pragma unroll
            for (int kk = 0; kk < 4; ++kk)
                bfr[ni][kk] = *(const bf16x8*)(WcT + (size_t)n * 256 + kk * 32 + lq * 8);
        }

        // ---- main GEMM half 0 (kc 0..3)
        f32x4 accM[4][4];
#pragma unroll
        for (int mi = 0; mi < 4; ++mi)
#pragma unroll
            for (int ni = 0; ni < 4; ++ni) accM[mi][ni] = z4;
#pragma unroll
        for (int kk = 0; kk < 4; ++kk) {
            const int kb = (kk * 32 + lq * 8) ^ swz;
            bf16x8 afr[4];
#pragma unroll
            for (int mi = 0; mi < 4; ++mi)
                afr[mi] = *(const bf16x8*)&Xh[(mi * 16 + l16) * 256 + kb];
#pragma unroll
            for (int mi = 0; mi < 4; ++mi)
#pragma unroll
                for (int ni = 0; ni < 4; ++ni)
                    accM[mi][ni] = __builtin_amdgcn_mfma_f32_16x16x32_bf16(
                        afr[mi], bfr[ni][kk], accM[mi][ni], 0, 0, 0);
        }

        // ---- B half 1 issue (flies during gram)
#pragma unroll
        for (int ni = 0; ni < 4; ++ni) {
            const int n = nb + ni * 16 + l16;
#pragma unroll
            for (int kk = 0; kk < 4; ++kk)
                bfr[ni][kk] = *(const bf16x8*)(WcT + (size_t)n * 256 + (4 + kk) * 32 + lq * 8);
        }

        // ---- gram (hi/lo), tile-row w
        f32x4 accG[4];
#pragma unroll
        for (int ni = 0; ni < 4; ++ni) accG[ni] = z4;
        const int arow = 16 * w + l16;
#pragma unroll
        for (int kc = 0; kc < 8; ++kc) {
            const int kb = (kc * 32 + lq * 8) ^ swz;
            const bf16x8 ah = *(const bf16x8*)&Xh[arow * 256 + kb];
            const bf16x8 al = *(const bf16x8*)&Xl[arow * 256 + kb];
#pragma unroll
            for (int ni = 0; ni < 4; ++ni) {
                const int brow = 16 * ni + l16;
                const bf16x8 bh = *(const bf16x8*)&Xh[brow * 256 + kb];
                const bf16x8 bl = *(const bf16x8*)&Xl[brow * 256 + kb];
                accG[ni] = __builtin_amdgcn_mfma_f32_16x16x32_bf16(ah, bh, accG[ni], 0, 0, 0);
                accG[ni] = __builtin_amdgcn_mfma_f32_16x16x32_bf16(ah, bl, accG[ni], 0, 0, 0);
                accG[ni] = __builtin_amdgcn_mfma_f32_16x16x32_bf16(al, bh, accG[ni], 0, 0, 0);
            }
        }

        // ---- main GEMM half 1 (kc 4..7)
#pragma unroll
        for (int kk = 0; kk < 4; ++kk) {
            const int kb = ((4 + kk) * 32 + lq * 8) ^ swz;
            bf16x8 afr[4];
#pragma unroll
            for (int mi = 0; mi < 4; ++mi)
                afr[mi] = *(const bf16x8*)&Xh[(mi * 16 + l16) * 256 + kb];
#pragma unroll
            for (int mi = 0; mi < 4; ++mi)
#pragma unroll
                for (int ni = 0; ni < 4; ++ni)
                    accM[mi][ni] = __builtin_amdgcn_mfma_f32_16x16x32_bf16(
                        afr[mi], bfr[ni][kk], accM[mi][ni], 0, 0, 0);
        }

        // ---- moments: col 63 (S) from tile ni=3; diag (SS) from tile ni=w
        if (l16 == 15) {
#pragma unroll
            for (int r = 0; r < 4; ++r) sS[16 * w + lq * 4 + r] = accG[3][r];
        }
        if ((l16 >> 2) == lq) ssS[16 * w + l16] = accG[w][l16 & 3];
        __syncthreads();   // barrier 2: moments in LDS
        if (t < 64) {
            const float S = sS[t], SSv = ssS[t];
            float m = S * (1.f / (float)NF);
            const float var = (SSv - S * S * (1.f / (float)NF)) * (1.f / (float)(NF - 1));
            float sc = 1.f / (sqrtf(var) + 1e-8f);
            if (t >= NC) { m = 0.f; sc = 0.f; }
            meanv[t] = m; sclv[t] = sc;
        }
        __syncthreads();   // barrier 3: meanv/sclv ready

        // ---- gram fixup + accumulate
        float mr[4], sr[4];
#pragma unroll
        for (int r = 0; r < 4; ++r) {
            const int row = 16 * w + lq * 4 + r;
            mr[r] = meanv[row]; sr[r] = sclv[row];
        }
#pragma unroll
        for (int ni = 0; ni < 4; ++ni) {
            const float mc = meanv[16 * ni + l16];
            const float sc = sclv[16 * ni + l16];
#pragma unroll
            for (int r = 0; r < 4; ++r)
                adjacc[ni][r] += (accG[ni][r] - (float)NF * mr[r] * mc) * sr[r] * sc;
        }

        // ---- main stores: rows 0..62 of this batch
        const size_t ob = (size_t)b * NC;
#pragma unroll
        for (int mi = 0; mi < 4; ++mi) {
#pragma unroll
            for (int r = 0; r < 4; ++r) {
                const int rt = mi * 16 + lq * 4 + r;
                if (rt < NC) {
#pragma unroll
                    for (int ni = 0; ni < 4; ++ni) {
                        const int col = nb + ni * 16 + l16;
                        if (col < ND)
                            out[(ob + rt) * ND + col] = accM[mi][ni][r] + bc[ni];
                    }
                }
            }
        }
    }

    // ---- write block gram partial [64][64]
#pragma unroll
    for (int ni = 0; ni < 4; ++ni)
#pragma unroll
        for (int r = 0; r < 4; ++r) {
            const int row = 16 * w + lq * 4 + r;
            const int col = 16 * ni + l16;
            partial[(size_t)blockIdx.x * 4096 + row * 64 + col] = adjacc[ni][r];
        }
}

// ============================================================================
// Reduce 512 partials -> adj (63x63). grid 63 rows x 512 thr.
// ============================================================================
__global__ __launch_bounds__(512) void k_adj_reduce(const float* __restrict__ partial,
                                                    float* __restrict__ adj) {
    __shared__ float red[8][64];
    const int row = blockIdx.x, t = threadIdx.x;
    const int c = t & 63, g = t >> 6;
    float s = 0.f;
    const float* p = partial + (size_t)(g * 64) * 4096 + row * 64 + c;
#pragma unroll 8
    for (int i = 0; i < 64; ++i) s += p[(size_t)i * 4096];
    red[g][c] = s;
    __syncthreads();
    if (t < NC) {
        float tot = 0.f;
#pragma unroll
        for (int gg = 0; gg < 8; ++gg) tot += red[gg][t];
        adj[row * NC + t] = tot * (1.f / ((float)NF * (float)NB));
    }
}

// ============================================================================
// k_gs: gs[f][h] = Wg[f, h-slice] . att_src[h],  gd likewise. (unchanged)
// ============================================================================
__global__ __launch_bounds__(256) void k_gs(const float* __restrict__ Wg,
                                            const float* __restrict__ att_src,
                                            const float* __restrict__ att_dst,
                                            float* __restrict__ gs,
                                            float* __restrict__ gd) {
    const int f = blockIdx.x;
    const int h = threadIdx.x >> 6, l = threadIdx.x & 63;
    const float* wr = Wg + (size_t)f * NHD + h * ND;
    const float* sp = att_src + h * ND;
    const float* dp = att_dst + h * ND;
    float s = 0.f, d = 0.f;
#pragma unroll
    for (int q = 0; q < 4; ++q) {
        const int dd = l + q * 64;
        if (dd < ND) {
            const float wv = wr[dd];
            s += wv * sp[dd];
            d += wv * dp[dd];
        }
    }
#pragma unroll
    for (int off = 32; off >= 1; off >>= 1) {
        s += __shfl_down(s, off);
        d += __shfl_down(d, off);
    }
    if (l == 0) { gs[f * NH + h] = s; gd[f * NH + h] = d; }
}

// ============================================================================
// k_asad: as[c,h] = x0[c] . gs[:,h]. One block. (unchanged)
// ============================================================================
__global__ __launch_bounds__(512) void k_asad(const float* __restrict__ x,
                                              const float* __restrict__ gs,
                                              const float* __restrict__ gd,
                                              float* __restrict__ as_,
                                              float* __restrict__ ad_) {
    __shared__ float x0S[NC * NF];       // 61.5 KB
    __shared__ float gsS[NF * NH], gdS[NF * NH];
    const int t = threadIdx.x;
    for (int e = t; e < NC * NF; e += 512) x0S[e] = x[e];
    for (int e = t; e < NF * NH; e += 512) { gsS[e] = gs[e]; gdS[e] = gd[e]; }
    __syncthreads();
    if (t < NC * NH) {
        const int c = t >> 2, h = t & 3;
        float s = 0.f, d = 0.f;
#pragma unroll 5
        for (int f = 0; f < NF; ++f) {
            const float xv = x0S[c * NF + f];
            s += xv * gsS[f * NH + h];
            d += xv * gdS[f * NH + h];
        }
        as_[t] = s; ad_[t] = d;
    }
}

// ============================================================================
// k_out0 v4: register softmax + projection over hp (K=256). (unchanged)
// ============================================================================
__global__ __launch_bounds__(512) void k_out0(const float* __restrict__ adj,
                                              const float* __restrict__ as_,
                                              const float* __restrict__ ad_,
                                              const float* __restrict__ hp,
                                              const float* __restrict__ biasc,
                                              float* __restrict__ out) {
    __shared__ float adjS[NC * NC];
    __shared__ float thS[NC];
    __shared__ float asS[NC * 5];        // stride-5 pad
    __shared__ float adS[NC * NH];
    __shared__ float wS[256];            // w[h*64+i], zeros at i=63
    __shared__ float psum[2][256];
    const int j = blockIdx.x, t = threadIdx.x;
    const int w = t >> 6, l = t & 63;

    for (int e = t; e < NC * NC; e += 512) adjS[e] = adj[e];
    if (t < NC * NH) { asS[(t >> 2) * 5 + (t & 3)] = as_[t]; adS[t] = ad_[t]; }
    __syncthreads();

    for (int r = w; r < NC; r += 8) {
        const float v = (l < NC) ? adjS[r * NC + l] : -INFINITY;
        float prev = INFINITY;
        int krem = 8;                     // TOP_K
        float th = -INFINITY;
#pragma unroll
        for (int iter = 0; iter < 8; ++iter) {
            const float vm = (v < prev) ? v : -INFINITY;
            float m = vm;
#pragma unroll
            for (int off = 32; off >= 1; off >>= 1) m = fmaxf(m, __shfl_xor(m, off));
            const unsigned long long b = __ballot(vm == m);
            const int cnt = __popcll(b);
            if (cnt >= krem) { th = m; break; }
            krem -= cnt; prev = m;
        }
        if (l == 0) thS[r] = th;
    }
    __syncthreads();

    if (w < NH) {
        const int h = w, i = l;
        const float adv = adS[j * NH + h];
        const float a = (i < NC) ? adjS[i * NC + j] : 0.f;
        const bool msk = (i < NC) && ((i == j) || ((a >= thS[i]) && (a != 0.f)));
        float e = 0.f;
        if (msk) { e = asS[i * 5 + h] + adv; e = e > 0.f ? e : 0.2f * e; }
        float m = msk ? e : -INFINITY;
#pragma unroll
        for (int off = 32; off >= 1; off >>= 1) m = fmaxf(m, __shfl_xor(m, off));
        const float p = msk ? __expf(e - m) : 0.f;
        float s = p;
#pragma unroll
        for (int off = 32; off >= 1; off >>= 1) s += __shfl_xor(s, off);
        wS[(h << 6) + l] = p / s;        // 0 for i=63 / unmasked
    }
    __syncthreads();

    const int q = t >> 8, col = t & 255;
    float acc = 0.f;
    const float* hpc = hp + col;
#pragma unroll 8
    for (int e = q * 128; e < q * 128 + 128; ++e)
        acc += wS[e] * hpc[(size_t)e * 256];
    psum[q][col] = acc;
    __syncthreads();
    if (t < ND) out[(size_t)j * ND + t] = psum[0][t] + psum[1][t] + biasc[t];
}

// ============================================================================
// Wc split-K x8 partials, stored TRANSPOSED pWcT[kq][n][256f]. (unchanged)
// ============================================================================
__global__ __launch_bounds__(256) void k_wc_part(const float* __restrict__ Wg,
                                                 const float* __restrict__ bias_gat,
                                                 const float* __restrict__ Wp,
                                                 float* __restrict__ pWcT,
                                                 float* __restrict__ pbias) {
    __shared__ float rows[250];
    const int b = blockIdx.x, t = threadIdx.x;
    if (b < 1000) {
        const int fb = (b >> 3) * 2, kq = b & 7;
        if (t < 250)
            rows[t] = Wg[(size_t)(fb + t / 125) * NHD + kq * 125 + (t % 125)];
        __syncthreads();
        if (t < ND) {
            float a0 = 0.f, a1 = 0.f;
            const float* wp = Wp + (size_t)(kq * 125) * ND + t;
            for (int k = 0; k < 125; ++k) {
                float wv = wp[(size_t)k * ND];
                a0 += rows[k] * wv;
                a1 += rows[125 + k] * wv;
            }
            pWcT[(size_t)kq * 65536 + (size_t)t * 256 + fb] = a0;
            pWcT[(size_t)kq * 65536 + (size_t)t * 256 + fb + 1] = a1;
        }
    } else {
        const int kq = b - 1000;
        if (t < ND) {
            float acc = 0.f;
            for (int k = kq * 125; k < kq * 125 + 125; ++k)
                acc += bias_gat[k] * Wp[(size_t)k * ND + t];
            pbias[kq * 256 + t] = acc;
        }
    }
}

// ============================================================================
// Combine: WcT + per-head WchT bf16; block 256 does biasc. (unchanged)
// ============================================================================
__global__ __launch_bounds__(256) void k_wct(const float* __restrict__ pWcT,
                                             const float* __restrict__ pbias,
                                             const float* __restrict__ b_proj,
                                             __bf16* __restrict__ WcT,
                                             __bf16* __restrict__ WchT,
                                             float* __restrict__ biasc) {
    const int n = blockIdx.x, t = threadIdx.x;
    if (n < 256) {
        float v[8];
        float tot = 0.f;
#pragma unroll
        for (int kq = 0; kq < 8; ++kq) {
            float xv = 0.f;
            if (n < ND && t < NF) xv = pWcT[(size_t)kq * 65536 + (size_t)n * 256 + t];
            v[kq] = xv; tot += xv;
        }
        WcT[n * 256 + t] = (__bf16)tot;
#pragma unroll
        for (int h = 0; h < NH; ++h)
            WchT[h * 65536 + n * 256 + t] = (__bf16)(v[2 * h] + v[2 * h + 1]);
    } else {
        if (t < ND) {
            float v = 0.f;
#pragma unroll
            for (int kq = 0; kq < 8; ++kq) v += pbias[kq * 256 + t];
            biasc[t] = v + b_proj[t];
        }
    }
}

// ============================================================================
// k_hp: hp[h*64+i][col] = x0[i] @ Wch[h] via MFMA (grid 4 = h). (unchanged)
// ============================================================================
__global__ __launch_bounds__(256) void k_hp(const float* __restrict__ x,
                                            const __bf16* __restrict__ WchT,
                                            float* __restrict__ hp) {
    __shared__ __align__(16) __bf16 Xs[64 * 256];
    const int h = blockIdx.x;
    const int t = threadIdx.x;
    const int w = t >> 6, l = t & 63;
    const int l16 = l & 15, lq = l >> 4;
    const int nb = w * 64;
    const int swz = (l16 & 7) << 3;

    bf16x8 bfr[4][8];
    const __bf16* Wh = WchT + h * 65536;
#pragma unroll
    for (int ni = 0; ni < 4; ++ni) {
        const int n = nb + ni * 16 + l16;
#pragma unroll
        for (int kc = 0; kc < 8; ++kc)
            bfr[ni][kc] = *(const bf16x8*)(Wh + (size_t)n * 256 + kc * 32 + lq * 8);
    }

#pragma unroll
    for (int it = 0; it < 8; ++it) {
        const int u = it * 256 + t;
        const int row = u >> 5;
        const int ko = (u & 31) << 3;
        float v[8];
#pragma unroll
        for (int q = 0; q < 4; ++q) { v[2 * q] = 0.f; v[2 * q + 1] = 0.f; }
        if (row < NC) {
            const float* src = x + row * NF + ko;
#pragma unroll
            for (int q = 0; q < 4; ++q) {
                if (ko + 2 * q + 1 < NF) {
                    const float2 p = *(const float2*)(src + 2 * q);
                    v[2 * q] = p.x; v[2 * q + 1] = p.y;
                }
            }
        }
        bf16x8 hv;
#pragma unroll
        for (int jj = 0; jj < 8; ++jj) hv[jj] = (__bf16)v[jj];
        *(bf16x8*)&Xs[row * 256 + (ko ^ ((row & 7) << 3))] = hv;
    }
    __syncthreads();

    f32x4 acc[4][4];
    const f32x4 z4 = {0.f, 0.f, 0.f, 0.f};
#pragma unroll
    for (int mi = 0; mi < 4; ++mi)
#pragma unroll
        for (int ni = 0; ni < 4; ++ni) acc[mi][ni] = z4;

#pragma unroll
    for (int kc = 0; kc < 8; ++kc) {
        const int kb = (kc * 32 + lq * 8) ^ swz;
        bf16x8 afr[4];
#pragma unroll
        for (int mi = 0; mi < 4; ++mi)
            afr[mi] = *(const bf16x8*)&Xs[(mi * 16 + l16) * 256 + kb];
#pragma unroll
        for (int mi = 0; mi < 4; ++mi)
#pragma unroll
            for (int ni = 0; ni < 4; ++ni)
                acc[mi][ni] = __builtin_amdgcn_mfma_f32_16x16x32_bf16(
                    afr[mi], bfr[ni][kc], acc[mi][ni], 0, 0, 0);
    }

#pragma unroll
    for (int mi = 0; mi < 4; ++mi)
#pragma unroll
        for (int r = 0; r < 4; ++r) {
            const int row = mi * 16 + lq * 4 + r;
#pragma unroll
            for (int ni = 0; ni < 4; ++ni) {
                const int col = nb + ni * 16 + l16;
                hp[(size_t)(h * 64 + row) * 256 + col] = acc[mi][ni][r];
            }
        }
}

// ============================================================================
extern "C" void kernel_launch(void* const* d_in, const int* in_sizes, int n_in,
                              void* d_out, int out_size, void* d_ws, size_t ws_size,
                              hipStream_t stream) {
    const float* x       = (const float*)d_in[0];
    const float* Wg      = (const float*)d_in[1];
    const float* att_src = (const float*)d_in[2];
    const float* att_dst = (const float*)d_in[3];
    const float* bias_g  = (const float*)d_in[4];
    const float* Wp      = (const float*)d_in[5];
    const float* b_proj  = (const float*)d_in[6];
    float* out = (float*)d_out;
    float* ws  = (float*)d_ws;

    __bf16* WcT    = (__bf16*)ws;                 // 65536 bf16  = 32768 f
    __bf16* WchT   = (__bf16*)(ws + 32768);       // 4*65536 bf16 = 131072 f
    float* pWcT    = ws + 32768 + 131072;         // 8*65536 = 524288
    float* pbias   = pWcT + 8 * 65536;            // 2048
    float* biasc   = pbias + 2048;                // 256
    float* partial = biasc + 256;                 // 512*4096 = 2,097,152
    float* adj     = partial + 512 * 4096;        // 3969
    float* hp      = adj + NC * NC;               // 256*256 = 65536
    float* gs      = hp + 65536;                  // 1000
    float* gd      = gs + 1000;                   // 1000
    float* as_     = gd + 1000;                   // 252
    float* ad_     = as_ + 252;                   // 252  (total ~11.4 MB)

    k_wc_part<<<1008, 256, 0, stream>>>(Wg, bias_g, Wp, pWcT, pbias);
    k_wct<<<257, 256, 0, stream>>>(pWcT, pbias, b_proj, WcT, WchT, biasc);
    k_fused<<<512, 256, 0, stream>>>(x, WcT, biasc, out, partial);
    k_adj_reduce<<<63, 512, 0, stream>>>(partial, adj);
    k_gs<<<250, 256, 0, stream>>>(Wg, att_src, att_dst, gs, gd);
    k_asad<<<1, 512, 0, stream>>>(x, gs, gd, as_, ad_);
    k_hp<<<4, 256, 0, stream>>>(x, WchT, hp);
    k_out0<<<63, 512, 0, stream>>>(adj, as_, ad_, hp, biasc, out);
}

// Round 11
// 126.774 us; speedup vs baseline: 1.2105x; 1.0413x over previous
//
#include <hip/hip_runtime.h>
#include <math.h>

#define NB 1024
#define NC 63
#define NF 250
#define NH 4
#define ND 250
#define NHD 1000

typedef __bf16 bf16x8 __attribute__((ext_vector_type(8)));
typedef float f32x4 __attribute__((ext_vector_type(4)));

// ============================================================================
// k_fused v2: per-batch {main GEMM + gram} off ONE staged x-tile.
// R10->R11 changes (theory: LDS-pipe pressure + 64KB-boundary residency):
//  1) UNIFIED fragment reads: main-A rows {16mi+l16} == gram-B rows
//     {16ni+l16}; read hi[4]/lo[4] once per kc (10 b128/kc vs 14).
//  2) LDS == exactly 65536B: moment arrays overlay Xh rows 0-1 (dead after
//     compute; +1 barrier before overlay write; rows restaged each batch).
// grid 512 x 256 thr (4 waves); 2 batches/block serial.
// ============================================================================
__global__ __launch_bounds__(256) void k_fused(const float* __restrict__ x,
                                               const __bf16* __restrict__ WcT,
                                               const float* __restrict__ biasc,
                                               float* __restrict__ out,
                                               float* __restrict__ partial) {
    __shared__ __align__(16) __bf16 Xh[64 * 256];   // 32 KB (rows 0-1 overlay moments post-compute)
    __shared__ __align__(16) __bf16 Xl[64 * 256];   // 32 KB
    float* const momS = (float*)Xh;  // [0:64)=S [64:128)=SS [128:192)=mean [192:256)=scl
    const int t = threadIdx.x;
    const int w = t >> 6, l = t & 63;
    const int l16 = l & 15, lq = l >> 4;
    const int swz = (l16 & 7) << 3;
    const int nb = w * 64;

    // ones row (row 63): hi=1, lo=0 at swizzled positions (set once)
    {
        const int kz = t ^ 56;                 // (63&7)<<3
        Xh[63 * 256 + kz] = (__bf16)1.0f;
        Xl[63 * 256 + kz] = (__bf16)0.0f;
    }

    float bc[4];
#pragma unroll
    for (int ni = 0; ni < 4; ++ni) {
        const int col = nb + ni * 16 + l16;
        bc[ni] = (col < ND) ? biasc[col] : 0.f;
    }

    float adjacc[4][4];
#pragma unroll
    for (int ni = 0; ni < 4; ++ni)
#pragma unroll
        for (int r = 0; r < 4; ++r) adjacc[ni][r] = 0.f;

    const f32x4 z4 = {0.f, 0.f, 0.f, 0.f};

    for (int bb = 0; bb < 2; ++bb) {
        const int b = blockIdx.x * 2 + bb;
        const float* xb = x + (size_t)b * (NC * NF);
        __syncthreads();   // protect planes (incl. moment overlay) from prior readers

        // ---- stage: 63 rows x 32 octets, coalesced float2 -> hi/lo bf16
#pragma unroll
        for (int it = 0; it < 8; ++it) {
            const int u = it * 256 + t;
            if (u < 2016) {
                const int row = u >> 5;
                const int ko = (u & 31) << 3;
                const float* src = xb + row * NF + ko;
                float v[8];
#pragma unroll
                for (int q = 0; q < 4; ++q) {
                    if (ko + q * 2 < NF) {
                        const float2 p = *(const float2*)(src + q * 2);
                        v[2 * q] = p.x; v[2 * q + 1] = p.y;
                    } else { v[2 * q] = 0.f; v[2 * q + 1] = 0.f; }
                }
                bf16x8 h, lo_;
#pragma unroll
                for (int j = 0; j < 8; ++j) {
                    h[j] = (__bf16)v[j];
                    lo_[j] = (__bf16)(v[j] - (float)h[j]);
                }
                const int kS = ko ^ ((row & 7) << 3);
                *(bf16x8*)&Xh[row * 256 + kS] = h;
                *(bf16x8*)&Xl[row * 256 + kS] = lo_;
            }
        }
        __syncthreads();   // staging complete

        bf16x8 bfr[4][4];
        f32x4 accM[4][4];
        f32x4 accG[4];
#pragma unroll
        for (int mi = 0; mi < 4; ++mi)
#pragma unroll
            for (int ni = 0; ni < 4; ++ni) accM[mi][ni] = z4;
#pragma unroll
        for (int ni = 0; ni < 4; ++ni) accG[ni] = z4;

        const int garow = (16 * w + l16) * 256;   // gram A row base

        // ================= K half 0 (kc 0..3) =================
#pragma unroll
        for (int ni = 0; ni < 4; ++ni) {
            const int n = nb + ni * 16 + l16;
#pragma unroll
            for (int kk = 0; kk < 4; ++kk)
                bfr[ni][kk] = *(const bf16x8*)(WcT + (size_t)n * 256 + kk * 32 + lq * 8);
        }
#pragma unroll
        for (int kk = 0; kk < 4; ++kk) {
            const int kb = (kk * 32 + lq * 8) ^ swz;
            bf16x8 hi[4], lo[4];
#pragma unroll
            for (int r = 0; r < 4; ++r) {
                hi[r] = *(const bf16x8*)&Xh[(r * 16 + l16) * 256 + kb];
                lo[r] = *(const bf16x8*)&Xl[(r * 16 + l16) * 256 + kb];
            }
            const bf16x8 ah = *(const bf16x8*)&Xh[garow + kb];
            const bf16x8 al = *(const bf16x8*)&Xl[garow + kb];
#pragma unroll
            for (int mi = 0; mi < 4; ++mi)
#pragma unroll
                for (int ni = 0; ni < 4; ++ni)
                    accM[mi][ni] = __builtin_amdgcn_mfma_f32_16x16x32_bf16(
                        hi[mi], bfr[ni][kk], accM[mi][ni], 0, 0, 0);
#pragma unroll
            for (int ni = 0; ni < 4; ++ni) {
                accG[ni] = __builtin_amdgcn_mfma_f32_16x16x32_bf16(ah, hi[ni], accG[ni], 0, 0, 0);
                accG[ni] = __builtin_amdgcn_mfma_f32_16x16x32_bf16(ah, lo[ni], accG[ni], 0, 0, 0);
                accG[ni] = __builtin_amdgcn_mfma_f32_16x16x32_bf16(al, hi[ni], accG[ni], 0, 0, 0);
            }
        }

        // ================= K half 1 (kc 4..7) =================
#pragma unroll
        for (int ni = 0; ni < 4; ++ni) {
            const int n = nb + ni * 16 + l16;
#pragma unroll
            for (int kk = 0; kk < 4; ++kk)
                bfr[ni][kk] = *(const bf16x8*)(WcT + (size_t)n * 256 + (4 + kk) * 32 + lq * 8);
        }
#pragma unroll
        for (int kk = 0; kk < 4; ++kk) {
            const int kb = ((4 + kk) * 32 + lq * 8) ^ swz;
            bf16x8 hi[4], lo[4];
#pragma unroll
            for (int r = 0; r < 4; ++r) {
                hi[r] = *(const bf16x8*)&Xh[(r * 16 + l16) * 256 + kb];
                lo[r] = *(const bf16x8*)&Xl[(r * 16 + l16) * 256 + kb];
            }
            const bf16x8 ah = *(const bf16x8*)&Xh[garow + kb];
            const bf16x8 al = *(const bf16x8*)&Xl[garow + kb];
#pragma unroll
            for (int mi = 0; mi < 4; ++mi)
#pragma unroll
                for (int ni = 0; ni < 4; ++ni)
                    accM[mi][ni] = __builtin_amdgcn_mfma_f32_16x16x32_bf16(
                        hi[mi], bfr[ni][kk], accM[mi][ni], 0, 0, 0);
#pragma unroll
            for (int ni = 0; ni < 4; ++ni) {
                accG[ni] = __builtin_amdgcn_mfma_f32_16x16x32_bf16(ah, hi[ni], accG[ni], 0, 0, 0);
                accG[ni] = __builtin_amdgcn_mfma_f32_16x16x32_bf16(ah, lo[ni], accG[ni], 0, 0, 0);
                accG[ni] = __builtin_amdgcn_mfma_f32_16x16x32_bf16(al, hi[ni], accG[ni], 0, 0, 0);
            }
        }

        __syncthreads();   // ALL plane reads done before overlay write (alias hazard)

        // ---- moments into overlay: col 63 (S) from tile ni=3; diag (SS)
        if (l16 == 15) {
#pragma unroll
            for (int r = 0; r < 4; ++r) momS[16 * w + lq * 4 + r] = accG[3][r];
        }
        if ((l16 >> 2) == lq) momS[64 + 16 * w + l16] = accG[w][l16 & 3];
        __syncthreads();
        if (t < 64) {
            const float S = momS[t], SSv = momS[64 + t];
            float m = S * (1.f / (float)NF);
            const float var = (SSv - S * S * (1.f / (float)NF)) * (1.f / (float)(NF - 1));
            float sc = 1.f / (sqrtf(var) + 1e-8f);
            if (t >= NC) { m = 0.f; sc = 0.f; }
            momS[128 + t] = m; momS[192 + t] = sc;
        }
        __syncthreads();

        // ---- gram fixup + accumulate
        float mr[4], sr[4];
#pragma unroll
        for (int r = 0; r < 4; ++r) {
            const int row = 16 * w + lq * 4 + r;
            mr[r] = momS[128 + row]; sr[r] = momS[192 + row];
        }
#pragma unroll
        for (int ni = 0; ni < 4; ++ni) {
            const float mc = momS[128 + 16 * ni + l16];
            const float sc = momS[192 + 16 * ni + l16];
#pragma unroll
            for (int r = 0; r < 4; ++r)
                adjacc[ni][r] += (accG[ni][r] - (float)NF * mr[r] * mc) * sr[r] * sc;
        }

        // ---- main stores: rows 0..62 of this batch
        const size_t ob = (size_t)b * NC;
#pragma unroll
        for (int mi = 0; mi < 4; ++mi) {
#pragma unroll
            for (int r = 0; r < 4; ++r) {
                const int rt = mi * 16 + lq * 4 + r;
                if (rt < NC) {
#pragma unroll
                    for (int ni = 0; ni < 4; ++ni) {
                        const int col = nb + ni * 16 + l16;
                        if (col < ND)
                            out[(ob + rt) * ND + col] = accM[mi][ni][r] + bc[ni];
                    }
                }
            }
        }
    }

    // ---- write block gram partial [64][64]
#pragma unroll
    for (int ni = 0; ni < 4; ++ni)
#pragma unroll
        for (int r = 0; r < 4; ++r) {
            const int row = 16 * w + lq * 4 + r;
            const int col = 16 * ni + l16;
            partial[(size_t)blockIdx.x * 4096 + row * 64 + col] = adjacc[ni][r];
        }
}

// ============================================================================
// Reduce 512 partials -> adj (63x63). grid 63 rows x 512 thr. (unchanged)
// ============================================================================
__global__ __launch_bounds__(512) void k_adj_reduce(const float* __restrict__ partial,
                                                    float* __restrict__ adj) {
    __shared__ float red[8][64];
    const int row = blockIdx.x, t = threadIdx.x;
    const int c = t & 63, g = t >> 6;
    float s = 0.f;
    const float* p = partial + (size_t)(g * 64) * 4096 + row * 64 + c;
#pragma unroll 8
    for (int i = 0; i < 64; ++i) s += p[(size_t)i * 4096];
    red[g][c] = s;
    __syncthreads();
    if (t < NC) {
        float tot = 0.f;
#pragma unroll
        for (int gg = 0; gg < 8; ++gg) tot += red[gg][t];
        adj[row * NC + t] = tot * (1.f / ((float)NF * (float)NB));
    }
}

// ============================================================================
// k_gs: gs[f][h] = Wg[f, h-slice] . att_src[h],  gd likewise. (unchanged)
// ============================================================================
__global__ __launch_bounds__(256) void k_gs(const float* __restrict__ Wg,
                                            const float* __restrict__ att_src,
                                            const float* __restrict__ att_dst,
                                            float* __restrict__ gs,
                                            float* __restrict__ gd) {
    const int f = blockIdx.x;
    const int h = threadIdx.x >> 6, l = threadIdx.x & 63;
    const float* wr = Wg + (size_t)f * NHD + h * ND;
    const float* sp = att_src + h * ND;
    const float* dp = att_dst + h * ND;
    float s = 0.f, d = 0.f;
#pragma unroll
    for (int q = 0; q < 4; ++q) {
        const int dd = l + q * 64;
        if (dd < ND) {
            const float wv = wr[dd];
            s += wv * sp[dd];
            d += wv * dp[dd];
        }
    }
#pragma unroll
    for (int off = 32; off >= 1; off >>= 1) {
        s += __shfl_down(s, off);
        d += __shfl_down(d, off);
    }
    if (l == 0) { gs[f * NH + h] = s; gd[f * NH + h] = d; }
}

// ============================================================================
// k_asad: as[c,h] = x0[c] . gs[:,h]. One block. (unchanged)
// ============================================================================
__global__ __launch_bounds__(512) void k_asad(const float* __restrict__ x,
                                              const float* __restrict__ gs,
                                              const float* __restrict__ gd,
                                              float* __restrict__ as_,
                                              float* __restrict__ ad_) {
    __shared__ float x0S[NC * NF];       // 61.5 KB
    __shared__ float gsS[NF * NH], gdS[NF * NH];
    const int t = threadIdx.x;
    for (int e = t; e < NC * NF; e += 512) x0S[e] = x[e];
    for (int e = t; e < NF * NH; e += 512) { gsS[e] = gs[e]; gdS[e] = gd[e]; }
    __syncthreads();
    if (t < NC * NH) {
        const int c = t >> 2, h = t & 3;
        float s = 0.f, d = 0.f;
#pragma unroll 5
        for (int f = 0; f < NF; ++f) {
            const float xv = x0S[c * NF + f];
            s += xv * gsS[f * NH + h];
            d += xv * gdS[f * NH + h];
        }
        as_[t] = s; ad_[t] = d;
    }
}

// ============================================================================
// k_out0 v4: register softmax + projection over hp (K=256). (unchanged)
// ============================================================================
__global__ __launch_bounds__(512) void k_out0(const float* __restrict__ adj,
                                              const float* __restrict__ as_,
                                              const float* __restrict__ ad_,
                                              const float* __restrict__ hp,
                                              const float* __restrict__ biasc,
                                              float* __restrict__ out) {
    __shared__ float adjS[NC * NC];
    __shared__ float thS[NC];
    __shared__ float asS[NC * 5];        // stride-5 pad
    __shared__ float adS[NC * NH];
    __shared__ float wS[256];            // w[h*64+i], zeros at i=63
    __shared__ float psum[2][256];
    const int j = blockIdx.x, t = threadIdx.x;
    const int w = t >> 6, l = t & 63;

    for (int e = t; e < NC * NC; e += 512) adjS[e] = adj[e];
    if (t < NC * NH) { asS[(t >> 2) * 5 + (t & 3)] = as_[t]; adS[t] = ad_[t]; }
    __syncthreads();

    for (int r = w; r < NC; r += 8) {
        const float v = (l < NC) ? adjS[r * NC + l] : -INFINITY;
        float prev = INFINITY;
        int krem = 8;                     // TOP_K
        float th = -INFINITY;
#pragma unroll
        for (int iter = 0; iter < 8; ++iter) {
            const float vm = (v < prev) ? v : -INFINITY;
            float m = vm;
#pragma unroll
            for (int off = 32; off >= 1; off >>= 1) m = fmaxf(m, __shfl_xor(m, off));
            const unsigned long long b = __ballot(vm == m);
            const int cnt = __popcll(b);
            if (cnt >= krem) { th = m; break; }
            krem -= cnt; prev = m;
        }
        if (l == 0) thS[r] = th;
    }
    __syncthreads();

    if (w < NH) {
        const int h = w, i = l;
        const float adv = adS[j * NH + h];
        const float a = (i < NC) ? adjS[i * NC + j] : 0.f;
        const bool msk = (i < NC) && ((i == j) || ((a >= thS[i]) && (a != 0.f)));
        float e = 0.f;
        if (msk) { e = asS[i * 5 + h] + adv; e = e > 0.f ? e : 0.2f * e; }
        float m = msk ? e : -INFINITY;
#pragma unroll
        for (int off = 32; off >= 1; off >>= 1) m = fmaxf(m, __shfl_xor(m, off));
        const float p = msk ? __expf(e - m) : 0.f;
        float s = p;
#pragma unroll
        for (int off = 32; off >= 1; off >>= 1) s += __shfl_xor(s, off);
        wS[(h << 6) + l] = p / s;        // 0 for i=63 / unmasked
    }
    __syncthreads();

    const int q = t >> 8, col = t & 255;
    float acc = 0.f;
    const float* hpc = hp + col;
#pragma unroll 8
    for (int e = q * 128; e < q * 128 + 128; ++e)
        acc += wS[e] * hpc[(size_t)e * 256];
    psum[q][col] = acc;
    __syncthreads();
    if (t < ND) out[(size_t)j * ND + t] = psum[0][t] + psum[1][t] + biasc[t];
}

// ============================================================================
// Wc split-K x8 partials, stored TRANSPOSED pWcT[kq][n][256f]. (unchanged)
// ============================================================================
__global__ __launch_bounds__(256) void k_wc_part(const float* __restrict__ Wg,
                                                 const float* __restrict__ bias_gat,
                                                 const float* __restrict__ Wp,
                                                 float* __restrict__ pWcT,
                                                 float* __restrict__ pbias) {
    __shared__ float rows[250];
    const int b = blockIdx.x, t = threadIdx.x;
    if (b < 1000) {
        const int fb = (b >> 3) * 2, kq = b & 7;
        if (t < 250)
            rows[t] = Wg[(size_t)(fb + t / 125) * NHD + kq * 125 + (t % 125)];
        __syncthreads();
        if (t < ND) {
            float a0 = 0.f, a1 = 0.f;
            const float* wp = Wp + (size_t)(kq * 125) * ND + t;
            for (int k = 0; k < 125; ++k) {
                float wv = wp[(size_t)k * ND];
                a0 += rows[k] * wv;
                a1 += rows[125 + k] * wv;
            }
            pWcT[(size_t)kq * 65536 + (size_t)t * 256 + fb] = a0;
            pWcT[(size_t)kq * 65536 + (size_t)t * 256 + fb + 1] = a1;
        }
    } else {
        const int kq = b - 1000;
        if (t < ND) {
            float acc = 0.f;
            for (int k = kq * 125; k < kq * 125 + 125; ++k)
                acc += bias_gat[k] * Wp[(size_t)k * ND + t];
            pbias[kq * 256 + t] = acc;
        }
    }
}

// ============================================================================
// Combine: WcT + per-head WchT bf16; block 256 does biasc. (unchanged)
// ============================================================================
__global__ __launch_bounds__(256) void k_wct(const float* __restrict__ pWcT,
                                             const float* __restrict__ pbias,
                                             const float* __restrict__ b_proj,
                                             __bf16* __restrict__ WcT,
                                             __bf16* __restrict__ WchT,
                                             float* __restrict__ biasc) {
    const int n = blockIdx.x, t = threadIdx.x;
    if (n < 256) {
        float v[8];
        float tot = 0.f;
#pragma unroll
        for (int kq = 0; kq < 8; ++kq) {
            float xv = 0.f;
            if (n < ND && t < NF) xv = pWcT[(size_t)kq * 65536 + (size_t)n * 256 + t];
            v[kq] = xv; tot += xv;
        }
        WcT[n * 256 + t] = (__bf16)tot;
#pragma unroll
        for (int h = 0; h < NH; ++h)
            WchT[h * 65536 + n * 256 + t] = (__bf16)(v[2 * h] + v[2 * h + 1]);
    } else {
        if (t < ND) {
            float v = 0.f;
#pragma unroll
            for (int kq = 0; kq < 8; ++kq) v += pbias[kq * 256 + t];
            biasc[t] = v + b_proj[t];
        }
    }
}

// ============================================================================
// k_hp: hp[h*64+i][col] = x0[i] @ Wch[h] via MFMA (grid 4 = h). (unchanged)
// ============================================================================
__global__ __launch_bounds__(256) void k_hp(const float* __restrict__ x,
                                            const __bf16* __restrict__ WchT,
                                            float* __restrict__ hp) {
    __shared__ __align__(16) __bf16 Xs[64 * 256];
    const int h = blockIdx.x;
    const int t = threadIdx.x;
    const int w = t >> 6, l = t & 63;
    const int l16 = l & 15, lq = l >> 4;
    const int nb = w * 64;
    const int swz = (l16 & 7) << 3;

    bf16x8 bfr[4][8];
    const __bf16* Wh = WchT + h * 65536;
#pragma unroll
    for (int ni = 0; ni < 4; ++ni) {
        const int n = nb + ni * 16 + l16;
#pragma unroll
        for (int kc = 0; kc < 8; ++kc)
            bfr[ni][kc] = *(const bf16x8*)(Wh + (size_t)n * 256 + kc * 32 + lq * 8);
    }

#pragma unroll
    for (int it = 0; it < 8; ++it) {
        const int u = it * 256 + t;
        const int row = u >> 5;
        const int ko = (u & 31) << 3;
        float v[8];
#pragma unroll
        for (int q = 0; q < 4; ++q) { v[2 * q] = 0.f; v[2 * q + 1] = 0.f; }
        if (row < NC) {
            const float* src = x + row * NF + ko;
#pragma unroll
            for (int q = 0; q < 4; ++q) {
                if (ko + 2 * q + 1 < NF) {
                    const float2 p = *(const float2*)(src + 2 * q);
                    v[2 * q] = p.x; v[2 * q + 1] = p.y;
                }
            }
        }
        bf16x8 hv;
#pragma unroll
        for (int jj = 0; jj < 8; ++jj) hv[jj] = (__bf16)v[jj];
        *(bf16x8*)&Xs[row * 256 + (ko ^ ((row & 7) << 3))] = hv;
    }
    __syncthreads();

    f32x4 acc[4][4];
    const f32x4 z4 = {0.f, 0.f, 0.f, 0.f};
#pragma unroll
    for (int mi = 0; mi < 4; ++mi)
#pragma unroll
        for (int ni = 0; ni < 4; ++ni) acc[mi][ni] = z4;

#pragma unroll
    for (int kc = 0; kc < 8; ++kc) {
        const int kb = (kc * 32 + lq * 8) ^ swz;
        bf16x8 afr[4];
#pragma unroll
        for (int mi = 0; mi < 4; ++mi)
            afr[mi] = *(const bf16x8*)&Xs[(mi * 16 + l16) * 256 + kb];
#pragma unroll
        for (int mi = 0; mi < 4; ++mi)
#pragma unroll
            for (int ni = 0; ni < 4; ++ni)
                acc[mi][ni] = __builtin_amdgcn_mfma_f32_16x16x32_bf16(
                    afr[mi], bfr[ni][kc], acc[mi][ni], 0, 0, 0);
    }

#pragma unroll
    for (int mi = 0; mi < 4; ++mi)
#pragma unroll
        for (int r = 0; r < 4; ++r) {
            const int row = mi * 16 + lq * 4 + r;
#pragma unroll
            for (int ni = 0; ni < 4; ++ni) {
                const int col = nb + ni * 16 + l16;
                hp[(size_t)(h * 64 + row) * 256 + col] = acc[mi][ni][r];
            }
        }
}

// ============================================================================
extern "C" void kernel_launch(void* const* d_in, const int* in_sizes, int n_in,
                              void* d_out, int out_size, void* d_ws, size_t ws_size,
                              hipStream_t stream) {
    const float* x       = (const float*)d_in[0];
    const float* Wg      = (const float*)d_in[1];
    const float* att_src = (const float*)d_in[2];
    const float* att_dst = (const float*)d_in[3];
    const float* bias_g  = (const float*)d_in[4];
    const float* Wp      = (const float*)d_in[5];
    const float* b_proj  = (const float*)d_in[6];
    float* out = (float*)d_out;
    float* ws  = (float*)d_ws;

    __bf16* WcT    = (__bf16*)ws;                 // 65536 bf16  = 32768 f
    __bf16* WchT   = (__bf16*)(ws + 32768);       // 4*65536 bf16 = 131072 f
    float* pWcT    = ws + 32768 + 131072;         // 8*65536 = 524288
    float* pbias   = pWcT + 8 * 65536;            // 2048
    float* biasc   = pbias + 2048;                // 256
    float* partial = biasc + 256;                 // 512*4096 = 2,097,152
    float* adj     = partial + 512 * 4096;        // 3969
    float* hp      = adj + NC * NC;               // 256*256 = 65536
    float* gs      = hp + 65536;                  // 1000
    float* gd      = gs + 1000;                   // 1000
    float* as_     = gd + 1000;                   // 252
    float* ad_     = as_ + 252;                   // 252  (total ~11.4 MB)

    k_wc_part<<<1008, 256, 0, stream>>>(Wg, bias_g, Wp, pWcT, pbias);
    k_wct<<<257, 256, 0, stream>>>(pWcT, pbias, b_proj, WcT, WchT, biasc);
    k_fused<<<512, 256, 0, stream>>>(x, WcT, biasc, out, partial);
    k_adj_reduce<<<63, 512, 0, stream>>>(partial, adj);
    k_gs<<<250, 256, 0, stream>>>(Wg, att_src, att_dst, gs, gd);
    k_asad<<<1, 512, 0, stream>>>(x, gs, gd, as_, ad_);
    k_hp<<<4, 256, 0, stream>>>(x, WchT, hp);
    k_out0<<<63, 512, 0, stream>>>(adj, as_, ad_, hp, biasc, out);
}

// Round 12
// 122.415 us; speedup vs baseline: 1.2536x; 1.0356x over previous
//
#include <hip/hip_runtime.h>
#include <math.h>

#define NB 1024
#define NC 63
#define NF 250
#define NH 4
#define ND 250
#define NHD 1000

typedef __bf16 bf16x8 __attribute__((ext_vector_type(8)));
typedef float f32x4 __attribute__((ext_vector_type(4)));

// ============================================================================
// k_fused v3: ONE batch per block (grid 1024).
// R11->R12 theory: the kernel is serial-chain latency-bound (all pipes <16%
// busy, occupancy ~10%, x is L3-resident). Halving per-block work and 4x-ing
// block count lets block turnover overlap stage-wait of one block with
// compute of another. adjacc regs dropped (fixup -> partial directly).
// ============================================================================
__global__ __launch_bounds__(256) void k_fused(const float* __restrict__ x,
                                               const __bf16* __restrict__ WcT,
                                               const float* __restrict__ biasc,
                                               float* __restrict__ out,
                                               float* __restrict__ partial) {
    __shared__ __align__(16) __bf16 Xh[64 * 256];   // 32 KB (rows 0-1 overlay moments post-compute)
    __shared__ __align__(16) __bf16 Xl[64 * 256];   // 32 KB
    float* const momS = (float*)Xh;  // [0:64)=S [64:128)=SS [128:192)=mean [192:256)=scl
    const int t = threadIdx.x;
    const int w = t >> 6, l = t & 63;
    const int l16 = l & 15, lq = l >> 4;
    const int swz = (l16 & 7) << 3;
    const int nb = w * 64;

    // ones row (row 63): hi=1, lo=0 at swizzled positions (disjoint addrs)
    {
        const int kz = t ^ 56;                 // (63&7)<<3
        Xh[63 * 256 + kz] = (__bf16)1.0f;
        Xl[63 * 256 + kz] = (__bf16)0.0f;
    }

    float bc[4];
#pragma unroll
    for (int ni = 0; ni < 4; ++ni) {
        const int col = nb + ni * 16 + l16;
        bc[ni] = (col < ND) ? biasc[col] : 0.f;
    }

    const f32x4 z4 = {0.f, 0.f, 0.f, 0.f};
    const int b = blockIdx.x;
    const float* xb = x + (size_t)b * (NC * NF);

    // ---- stage: 63 rows x 32 octets, coalesced float2 -> hi/lo bf16
#pragma unroll
    for (int it = 0; it < 8; ++it) {
        const int u = it * 256 + t;
        if (u < 2016) {
            const int row = u >> 5;
            const int ko = (u & 31) << 3;
            const float* src = xb + row * NF + ko;
            float v[8];
#pragma unroll
            for (int q = 0; q < 4; ++q) {
                if (ko + q * 2 < NF) {
                    const float2 p = *(const float2*)(src + q * 2);
                    v[2 * q] = p.x; v[2 * q + 1] = p.y;
                } else { v[2 * q] = 0.f; v[2 * q + 1] = 0.f; }
            }
            bf16x8 h, lo_;
#pragma unroll
            for (int j = 0; j < 8; ++j) {
                h[j] = (__bf16)v[j];
                lo_[j] = (__bf16)(v[j] - (float)h[j]);
            }
            const int kS = ko ^ ((row & 7) << 3);
            *(bf16x8*)&Xh[row * 256 + kS] = h;
            *(bf16x8*)&Xl[row * 256 + kS] = lo_;
        }
    }
    __syncthreads();   // staging complete

    bf16x8 bfr[4][4];
    f32x4 accM[4][4];
    f32x4 accG[4];
#pragma unroll
    for (int mi = 0; mi < 4; ++mi)
#pragma unroll
        for (int ni = 0; ni < 4; ++ni) accM[mi][ni] = z4;
#pragma unroll
    for (int ni = 0; ni < 4; ++ni) accG[ni] = z4;

    const int garow = (16 * w + l16) * 256;   // gram A row base

    // ================= K half 0 (kc 0..3) =================
#pragma unroll
    for (int ni = 0; ni < 4; ++ni) {
        const int n = nb + ni * 16 + l16;
#pragma unroll
        for (int kk = 0; kk < 4; ++kk)
            bfr[ni][kk] = *(const bf16x8*)(WcT + (size_t)n * 256 + kk * 32 + lq * 8);
    }
#pragma unroll
    for (int kk = 0; kk < 4; ++kk) {
        const int kb = (kk * 32 + lq * 8) ^ swz;
        bf16x8 hi[4], lo[4];
#pragma unroll
        for (int r = 0; r < 4; ++r) {
            hi[r] = *(const bf16x8*)&Xh[(r * 16 + l16) * 256 + kb];
            lo[r] = *(const bf16x8*)&Xl[(r * 16 + l16) * 256 + kb];
        }
        const bf16x8 ah = *(const bf16x8*)&Xh[garow + kb];
        const bf16x8 al = *(const bf16x8*)&Xl[garow + kb];
#pragma unroll
        for (int mi = 0; mi < 4; ++mi)
#pragma unroll
            for (int ni = 0; ni < 4; ++ni)
                accM[mi][ni] = __builtin_amdgcn_mfma_f32_16x16x32_bf16(
                    hi[mi], bfr[ni][kk], accM[mi][ni], 0, 0, 0);
#pragma unroll
        for (int ni = 0; ni < 4; ++ni) {
            accG[ni] = __builtin_amdgcn_mfma_f32_16x16x32_bf16(ah, hi[ni], accG[ni], 0, 0, 0);
            accG[ni] = __builtin_amdgcn_mfma_f32_16x16x32_bf16(ah, lo[ni], accG[ni], 0, 0, 0);
            accG[ni] = __builtin_amdgcn_mfma_f32_16x16x32_bf16(al, hi[ni], accG[ni], 0, 0, 0);
        }
    }

    // ================= K half 1 (kc 4..7) =================
#pragma unroll
    for (int ni = 0; ni < 4; ++ni) {
        const int n = nb + ni * 16 + l16;
#pragma unroll
        for (int kk = 0; kk < 4; ++kk)
            bfr[ni][kk] = *(const bf16x8*)(WcT + (size_t)n * 256 + (4 + kk) * 32 + lq * 8);
    }
#pragma unroll
    for (int kk = 0; kk < 4; ++kk) {
        const int kb = ((4 + kk) * 32 + lq * 8) ^ swz;
        bf16x8 hi[4], lo[4];
#pragma unroll
        for (int r = 0; r < 4; ++r) {
            hi[r] = *(const bf16x8*)&Xh[(r * 16 + l16) * 256 + kb];
            lo[r] = *(const bf16x8*)&Xl[(r * 16 + l16) * 256 + kb];
        }
        const bf16x8 ah = *(const bf16x8*)&Xh[garow + kb];
        const bf16x8 al = *(const bf16x8*)&Xl[garow + kb];
#pragma unroll
        for (int mi = 0; mi < 4; ++mi)
#pragma unroll
            for (int ni = 0; ni < 4; ++ni)
                accM[mi][ni] = __builtin_amdgcn_mfma_f32_16x16x32_bf16(
                    hi[mi], bfr[ni][kk], accM[mi][ni], 0, 0, 0);
#pragma unroll
        for (int ni = 0; ni < 4; ++ni) {
            accG[ni] = __builtin_amdgcn_mfma_f32_16x16x32_bf16(ah, hi[ni], accG[ni], 0, 0, 0);
            accG[ni] = __builtin_amdgcn_mfma_f32_16x16x32_bf16(ah, lo[ni], accG[ni], 0, 0, 0);
            accG[ni] = __builtin_amdgcn_mfma_f32_16x16x32_bf16(al, hi[ni], accG[ni], 0, 0, 0);
        }
    }

    __syncthreads();   // ALL plane reads done before overlay write (alias hazard)

    // ---- moments into overlay: col 63 (S) from tile ni=3; diag (SS)
    if (l16 == 15) {
#pragma unroll
        for (int r = 0; r < 4; ++r) momS[16 * w + lq * 4 + r] = accG[3][r];
    }
    if ((l16 >> 2) == lq) momS[64 + 16 * w + l16] = accG[w][l16 & 3];
    __syncthreads();
    if (t < 64) {
        const float S = momS[t], SSv = momS[64 + t];
        float m = S * (1.f / (float)NF);
        const float var = (SSv - S * S * (1.f / (float)NF)) * (1.f / (float)(NF - 1));
        float sc = 1.f / (sqrtf(var) + 1e-8f);
        if (t >= NC) { m = 0.f; sc = 0.f; }
        momS[128 + t] = m; momS[192 + t] = sc;
    }
    __syncthreads();

    // ---- gram fixup -> partial (direct, no carry regs)
    float mr[4], sr[4];
#pragma unroll
    for (int r = 0; r < 4; ++r) {
        const int row = 16 * w + lq * 4 + r;
        mr[r] = momS[128 + row]; sr[r] = momS[192 + row];
    }
#pragma unroll
    for (int ni = 0; ni < 4; ++ni) {
        const float mc = momS[128 + 16 * ni + l16];
        const float sc = momS[192 + 16 * ni + l16];
#pragma unroll
        for (int r = 0; r < 4; ++r) {
            const int row = 16 * w + lq * 4 + r;
            const int col = 16 * ni + l16;
            partial[(size_t)b * 4096 + row * 64 + col] =
                (accG[ni][r] - (float)NF * mr[r] * mc) * sr[r] * sc;
        }
    }

    // ---- main stores: rows 0..62 of this batch
    const size_t ob = (size_t)b * NC;
#pragma unroll
    for (int mi = 0; mi < 4; ++mi) {
#pragma unroll
        for (int r = 0; r < 4; ++r) {
            const int rt = mi * 16 + lq * 4 + r;
            if (rt < NC) {
#pragma unroll
                for (int ni = 0; ni < 4; ++ni) {
                    const int col = nb + ni * 16 + l16;
                    if (col < ND)
                        out[(ob + rt) * ND + col] = accM[mi][ni][r] + bc[ni];
                }
            }
        }
    }
}

// ============================================================================
// Reduce 1024 partials -> adj (63x63). grid 63 rows x 512 thr.
// ============================================================================
__global__ __launch_bounds__(512) void k_adj_reduce(const float* __restrict__ partial,
                                                    float* __restrict__ adj) {
    __shared__ float red[8][64];
    const int row = blockIdx.x, t = threadIdx.x;
    const int c = t & 63, g = t >> 6;
    float s = 0.f;
    const float* p = partial + (size_t)(g * 128) * 4096 + row * 64 + c;
#pragma unroll 8
    for (int i = 0; i < 128; ++i) s += p[(size_t)i * 4096];
    red[g][c] = s;
    __syncthreads();
    if (t < NC) {
        float tot = 0.f;
#pragma unroll
        for (int gg = 0; gg < 8; ++gg) tot += red[gg][t];
        adj[row * NC + t] = tot * (1.f / ((float)NF * (float)NB));
    }
}

// ============================================================================
// k_gs: gs[f][h] = Wg[f, h-slice] . att_src[h],  gd likewise. (unchanged)
// ============================================================================
__global__ __launch_bounds__(256) void k_gs(const float* __restrict__ Wg,
                                            const float* __restrict__ att_src,
                                            const float* __restrict__ att_dst,
                                            float* __restrict__ gs,
                                            float* __restrict__ gd) {
    const int f = blockIdx.x;
    const int h = threadIdx.x >> 6, l = threadIdx.x & 63;
    const float* wr = Wg + (size_t)f * NHD + h * ND;
    const float* sp = att_src + h * ND;
    const float* dp = att_dst + h * ND;
    float s = 0.f, d = 0.f;
#pragma unroll
    for (int q = 0; q < 4; ++q) {
        const int dd = l + q * 64;
        if (dd < ND) {
            const float wv = wr[dd];
            s += wv * sp[dd];
            d += wv * dp[dd];
        }
    }
#pragma unroll
    for (int off = 32; off >= 1; off >>= 1) {
        s += __shfl_down(s, off);
        d += __shfl_down(d, off);
    }
    if (l == 0) { gs[f * NH + h] = s; gd[f * NH + h] = d; }
}

// ============================================================================
// k_asad: as[c,h] = x0[c] . gs[:,h]. One block. (unchanged)
// ============================================================================
__global__ __launch_bounds__(512) void k_asad(const float* __restrict__ x,
                                              const float* __restrict__ gs,
                                              const float* __restrict__ gd,
                                              float* __restrict__ as_,
                                              float* __restrict__ ad_) {
    __shared__ float x0S[NC * NF];       // 61.5 KB
    __shared__ float gsS[NF * NH], gdS[NF * NH];
    const int t = threadIdx.x;
    for (int e = t; e < NC * NF; e += 512) x0S[e] = x[e];
    for (int e = t; e < NF * NH; e += 512) { gsS[e] = gs[e]; gdS[e] = gd[e]; }
    __syncthreads();
    if (t < NC * NH) {
        const int c = t >> 2, h = t & 3;
        float s = 0.f, d = 0.f;
#pragma unroll 5
        for (int f = 0; f < NF; ++f) {
            const float xv = x0S[c * NF + f];
            s += xv * gsS[f * NH + h];
            d += xv * gdS[f * NH + h];
        }
        as_[t] = s; ad_[t] = d;
    }
}

// ============================================================================
// k_out0 v4: register softmax + projection over hp (K=256). (unchanged)
// ============================================================================
__global__ __launch_bounds__(512) void k_out0(const float* __restrict__ adj,
                                              const float* __restrict__ as_,
                                              const float* __restrict__ ad_,
                                              const float* __restrict__ hp,
                                              const float* __restrict__ biasc,
                                              float* __restrict__ out) {
    __shared__ float adjS[NC * NC];
    __shared__ float thS[NC];
    __shared__ float asS[NC * 5];        // stride-5 pad
    __shared__ float adS[NC * NH];
    __shared__ float wS[256];            // w[h*64+i], zeros at i=63
    __shared__ float psum[2][256];
    const int j = blockIdx.x, t = threadIdx.x;
    const int w = t >> 6, l = t & 63;

    for (int e = t; e < NC * NC; e += 512) adjS[e] = adj[e];
    if (t < NC * NH) { asS[(t >> 2) * 5 + (t & 3)] = as_[t]; adS[t] = ad_[t]; }
    __syncthreads();

    for (int r = w; r < NC; r += 8) {
        const float v = (l < NC) ? adjS[r * NC + l] : -INFINITY;
        float prev = INFINITY;
        int krem = 8;                     // TOP_K
        float th = -INFINITY;
#pragma unroll
        for (int iter = 0; iter < 8; ++iter) {
            const float vm = (v < prev) ? v : -INFINITY;
            float m = vm;
#pragma unroll
            for (int off = 32; off >= 1; off >>= 1) m = fmaxf(m, __shfl_xor(m, off));
            const unsigned long long b = __ballot(vm == m);
            const int cnt = __popcll(b);
            if (cnt >= krem) { th = m; break; }
            krem -= cnt; prev = m;
        }
        if (l == 0) thS[r] = th;
    }
    __syncthreads();

    if (w < NH) {
        const int h = w, i = l;
        const float adv = adS[j * NH + h];
        const float a = (i < NC) ? adjS[i * NC + j] : 0.f;
        const bool msk = (i < NC) && ((i == j) || ((a >= thS[i]) && (a != 0.f)));
        float e = 0.f;
        if (msk) { e = asS[i * 5 + h] + adv; e = e > 0.f ? e : 0.2f * e; }
        float m = msk ? e : -INFINITY;
#pragma unroll
        for (int off = 32; off >= 1; off >>= 1) m = fmaxf(m, __shfl_xor(m, off));
        const float p = msk ? __expf(e - m) : 0.f;
        float s = p;
#pragma unroll
        for (int off = 32; off >= 1; off >>= 1) s += __shfl_xor(s, off);
        wS[(h << 6) + l] = p / s;        // 0 for i=63 / unmasked
    }
    __syncthreads();

    const int q = t >> 8, col = t & 255;
    float acc = 0.f;
    const float* hpc = hp + col;
#pragma unroll 8
    for (int e = q * 128; e < q * 128 + 128; ++e)
        acc += wS[e] * hpc[(size_t)e * 256];
    psum[q][col] = acc;
    __syncthreads();
    if (t < ND) out[(size_t)j * ND + t] = psum[0][t] + psum[1][t] + biasc[t];
}

// ============================================================================
// Wc split-K x8 partials, stored TRANSPOSED pWcT[kq][n][256f]. (unchanged)
// ============================================================================
__global__ __launch_bounds__(256) void k_wc_part(const float* __restrict__ Wg,
                                                 const float* __restrict__ bias_gat,
                                                 const float* __restrict__ Wp,
                                                 float* __restrict__ pWcT,
                                                 float* __restrict__ pbias) {
    __shared__ float rows[250];
    const int b = blockIdx.x, t = threadIdx.x;
    if (b < 1000) {
        const int fb = (b >> 3) * 2, kq = b & 7;
        if (t < 250)
            rows[t] = Wg[(size_t)(fb + t / 125) * NHD + kq * 125 + (t % 125)];
        __syncthreads();
        if (t < ND) {
            float a0 = 0.f, a1 = 0.f;
            const float* wp = Wp + (size_t)(kq * 125) * ND + t;
            for (int k = 0; k < 125; ++k) {
                float wv = wp[(size_t)k * ND];
                a0 += rows[k] * wv;
                a1 += rows[125 + k] * wv;
            }
            pWcT[(size_t)kq * 65536 + (size_t)t * 256 + fb] = a0;
            pWcT[(size_t)kq * 65536 + (size_t)t * 256 + fb + 1] = a1;
        }
    } else {
        const int kq = b - 1000;
        if (t < ND) {
            float acc = 0.f;
            for (int k = kq * 125; k < kq * 125 + 125; ++k)
                acc += bias_gat[k] * Wp[(size_t)k * ND + t];
            pbias[kq * 256 + t] = acc;
        }
    }
}

// ============================================================================
// Combine: WcT + per-head WchT bf16; block 256 does biasc. (unchanged)
// ============================================================================
__global__ __launch_bounds__(256) void k_wct(const float* __restrict__ pWcT,
                                             const float* __restrict__ pbias,
                                             const float* __restrict__ b_proj,
                                             __bf16* __restrict__ WcT,
                                             __bf16* __restrict__ WchT,
                                             float* __restrict__ biasc) {
    const int n = blockIdx.x, t = threadIdx.x;
    if (n < 256) {
        float v[8];
        float tot = 0.f;
#pragma unroll
        for (int kq = 0; kq < 8; ++kq) {
            float xv = 0.f;
            if (n < ND && t < NF) xv = pWcT[(size_t)kq * 65536 + (size_t)n * 256 + t];
            v[kq] = xv; tot += xv;
        }
        WcT[n * 256 + t] = (__bf16)tot;
#pragma unroll
        for (int h = 0; h < NH; ++h)
            WchT[h * 65536 + n * 256 + t] = (__bf16)(v[2 * h] + v[2 * h + 1]);
    } else {
        if (t < ND) {
            float v = 0.f;
#pragma unroll
            for (int kq = 0; kq < 8; ++kq) v += pbias[kq * 256 + t];
            biasc[t] = v + b_proj[t];
        }
    }
}

// ============================================================================
// k_hp: hp[h*64+i][col] = x0[i] @ Wch[h] via MFMA (grid 4 = h). (unchanged)
// ============================================================================
__global__ __launch_bounds__(256) void k_hp(const float* __restrict__ x,
                                            const __bf16* __restrict__ WchT,
                                            float* __restrict__ hp) {
    __shared__ __align__(16) __bf16 Xs[64 * 256];
    const int h = blockIdx.x;
    const int t = threadIdx.x;
    const int w = t >> 6, l = t & 63;
    const int l16 = l & 15, lq = l >> 4;
    const int nb = w * 64;
    const int swz = (l16 & 7) << 3;

    bf16x8 bfr[4][8];
    const __bf16* Wh = WchT + h * 65536;
#pragma unroll
    for (int ni = 0; ni < 4; ++ni) {
        const int n = nb + ni * 16 + l16;
#pragma unroll
        for (int kc = 0; kc < 8; ++kc)
            bfr[ni][kc] = *(const bf16x8*)(Wh + (size_t)n * 256 + kc * 32 + lq * 8);
    }

#pragma unroll
    for (int it = 0; it < 8; ++it) {
        const int u = it * 256 + t;
        const int row = u >> 5;
        const int ko = (u & 31) << 3;
        float v[8];
#pragma unroll
        for (int q = 0; q < 4; ++q) { v[2 * q] = 0.f; v[2 * q + 1] = 0.f; }
        if (row < NC) {
            const float* src = x + row * NF + ko;
#pragma unroll
            for (int q = 0; q < 4; ++q) {
                if (ko + 2 * q + 1 < NF) {
                    const float2 p = *(const float2*)(src + 2 * q);
                    v[2 * q] = p.x; v[2 * q + 1] = p.y;
                }
            }
        }
        bf16x8 hv;
#pragma unroll
        for (int jj = 0; jj < 8; ++jj) hv[jj] = (__bf16)v[jj];
        *(bf16x8*)&Xs[row * 256 + (ko ^ ((row & 7) << 3))] = hv;
    }
    __syncthreads();

    f32x4 acc[4][4];
    const f32x4 z4 = {0.f, 0.f, 0.f, 0.f};
#pragma unroll
    for (int mi = 0; mi < 4; ++mi)
#pragma unroll
        for (int ni = 0; ni < 4; ++ni) acc[mi][ni] = z4;

#pragma unroll
    for (int kc = 0; kc < 8; ++kc) {
        const int kb = (kc * 32 + lq * 8) ^ swz;
        bf16x8 afr[4];
#pragma unroll
        for (int mi = 0; mi < 4; ++mi)
            afr[mi] = *(const bf16x8*)&Xs[(mi * 16 + l16) * 256 + kb];
#pragma unroll
        for (int mi = 0; mi < 4; ++mi)
#pragma unroll
            for (int ni = 0; ni < 4; ++ni)
                acc[mi][ni] = __builtin_amdgcn_mfma_f32_16x16x32_bf16(
                    afr[mi], bfr[ni][kc], acc[mi][ni], 0, 0, 0);
    }

#pragma unroll
    for (int mi = 0; mi < 4; ++mi)
#pragma unroll
        for (int r = 0; r < 4; ++r) {
            const int row = mi * 16 + lq * 4 + r;
#pragma unroll
            for (int ni = 0; ni < 4; ++ni) {
                const int col = nb + ni * 16 + l16;
                hp[(size_t)(h * 64 + row) * 256 + col] = acc[mi][ni][r];
            }
        }
}

// ============================================================================
extern "C" void kernel_launch(void* const* d_in, const int* in_sizes, int n_in,
                              void* d_out, int out_size, void* d_ws, size_t ws_size,
                              hipStream_t stream) {
    const float* x       = (const float*)d_in[0];
    const float* Wg      = (const float*)d_in[1];
    const float* att_src = (const float*)d_in[2];
    const float* att_dst = (const float*)d_in[3];
    const float* bias_g  = (const float*)d_in[4];
    const float* Wp      = (const float*)d_in[5];
    const float* b_proj  = (const float*)d_in[6];
    float* out = (float*)d_out;
    float* ws  = (float*)d_ws;

    __bf16* WcT    = (__bf16*)ws;                 // 65536 bf16  = 32768 f
    __bf16* WchT   = (__bf16*)(ws + 32768);       // 4*65536 bf16 = 131072 f
    float* pWcT    = ws + 32768 + 131072;         // 8*65536 = 524288
    float* pbias   = pWcT + 8 * 65536;            // 2048
    float* biasc   = pbias + 2048;                // 256
    float* partial = biasc + 256;                 // 1024*4096 = 4,194,304
    float* adj     = partial + 1024 * 4096;       // 3969
    float* hp      = adj + NC * NC;               // 256*256 = 65536
    float* gs      = hp + 65536;                  // 1000
    float* gd      = gs + 1000;                   // 1000
    float* as_     = gd + 1000;                   // 252
    float* ad_     = as_ + 252;                   // 252  (total ~19.7 MB)

    k_wc_part<<<1008, 256, 0, stream>>>(Wg, bias_g, Wp, pWcT, pbias);
    k_wct<<<257, 256, 0, stream>>>(pWcT, pbias, b_proj, WcT, WchT, biasc);
    k_fused<<<1024, 256, 0, stream>>>(x, WcT, biasc, out, partial);
    k_adj_reduce<<<63, 512, 0, stream>>>(partial, adj);
    k_gs<<<250, 256, 0, stream>>>(Wg, att_src, att_dst, gs, gd);
    k_asad<<<1, 512, 0, stream>>>(x, gs, gd, as_, ad_);
    k_hp<<<4, 256, 0, stream>>>(x, WchT, hp);
    k_out0<<<63, 512, 0, stream>>>(adj, as_, ad_, hp, biasc, out);
}